// Round 12
// baseline (304.120 us; speedup 1.0000x reference)
//
#include <hip/hip_runtime.h>
#include <math.h>

#define NB 16      // B
#define NN 1024    // N
#define NF 32      // F
#define NT 12      // T
#define NFC 64
#define NFT 64

typedef __attribute__((ext_vector_type(8))) short bf16x8;
typedef __attribute__((ext_vector_type(4))) float f32x4;

__device__ inline unsigned short cvt_bf(float f) {
    unsigned int u = __float_as_uint(f);
    u += 0x7fff + ((u >> 16) & 1);
    return (unsigned short)(u >> 16);
}
__device__ inline float bf2f(unsigned short u) {
    return __uint_as_float(((unsigned int)u) << 16);
}
__device__ inline void gll16(const short* g, short* l) {
    __builtin_amdgcn_global_load_lds((const __attribute__((address_space(1))) void*)g,
                                     (__attribute__((address_space(3))) void*)l, 16, 0, 0);
}

// ---------------- fused pre-pass: lhs_pre (U1), rhs (U3), rr3 (W3), Xrow (bf16) ----------------
__global__ __launch_bounds__(384) void k_pre(const float* __restrict__ x,
                                             const float* __restrict__ U1,
                                             const float* __restrict__ U3,
                                             const float* __restrict__ W3,
                                             float* __restrict__ lhs_pre,
                                             float* __restrict__ rhs,
                                             float* __restrict__ rr3,
                                             unsigned short* __restrict__ Xrow)
{
    __shared__ float xs[8 * 384];
    int b = blockIdx.x, ch = blockIdx.y, tid = threadIdx.x;
    float acc = 0.f;
    for (int c8 = 0; c8 < 8; c8++) {
        int n0 = ch * 64 + c8 * 8;
        size_t r0 = (size_t)b * NN + n0;
        __syncthreads();
        for (int i = 0; i < 8; i++) xs[i * 384 + tid] = x[(r0 + i) * 384 + tid];
        __syncthreads();
        for (int i = 0; i < 8; i++) acc += xs[i * 384 + tid] * U1[n0 + i];
        for (int idx = tid; idx < 1536; idx += 384) {
            int row = idx / 192, jj = (idx - row * 192) * 2;
            unsigned int w = (unsigned int)cvt_bf(xs[row * 384 + jj])
                           | ((unsigned int)cvt_bf(xs[row * 384 + jj + 1]) << 16);
            *(unsigned int*)(Xrow + (r0 + row) * 384 + jj) = w;
        }
        if (tid < 192) {
            int half = tid / 96;
            int r = tid - half * 96;
            int i = r / 12, t = r - i * 12;
            const float* wv = half ? W3 : U3;
            float s = 0.f;
            for (int f = 0; f < 32; f++) s += wv[f] * xs[i * 384 + f * 12 + t];
            float* outp = half ? rr3 : rhs;
            outp[(r0 + i) * 12 + t] = s;
        }
    }
    int f = tid / 12, t = tid - f * 12;
    atomicAdd(&lhs_pre[b * 384 + t * 32 + f], acc);
}

// M2[b][f][u] = sum_n U2[f][n] * rhs[b][n][u]
__global__ __launch_bounds__(384) void k_M2(const float* __restrict__ U2,
                                            const float* __restrict__ rhs,
                                            float* __restrict__ M2)
{
    int b = blockIdx.x, ch = blockIdx.y, tid = threadIdx.x;
    int f = tid / 12, u = tid - (tid / 12) * 12;
    int n0 = ch * 32;
    float a = 0.f;
    for (int n = n0; n < n0 + 32; n++)
        a += U2[(size_t)f * NN + n] * rhs[((size_t)b * NN + n) * 12 + u];
    atomicAdd(&M2[b * 384 + f * 12 + u], a);
}

// E (softmax over t) + EW1; prod inline
__global__ __launch_bounds__(192) void k_E(const float* __restrict__ lhs_pre,
                                           const float* __restrict__ M2,
                                           const float* __restrict__ be,
                                           const float* __restrict__ Ve,
                                           const float* __restrict__ W1,
                                           float* __restrict__ E,
                                           float* __restrict__ EW1)
{
    int b = blockIdx.x, tid = threadIdx.x;
    __shared__ float lp2[384], m2s[384];
    __shared__ float ssig[144], sE[144], mx[12], sm[12];
    for (int i = tid; i < 384; i += 192) {
        lp2[i] = lhs_pre[b * 384 + i];
        m2s[i] = M2[b * 384 + i];
    }
    __syncthreads();
    if (tid < 144) {
        int s = tid / 12, u = tid - s * 12;
        float p = 0.f;
#pragma unroll
        for (int f = 0; f < 32; f++) p += lp2[s * 32 + f] * m2s[f * 12 + u];
        ssig[tid] = 1.f / (1.f + expf(-(p + be[tid])));
    }
    __syncthreads();
    if (tid < 144) {
        int t = tid / 12, u = tid - t * 12;
        float a = 0.f;
        for (int s2 = 0; s2 < 12; s2++) a += Ve[t * 12 + s2] * ssig[s2 * 12 + u];
        sE[tid] = a;
    }
    __syncthreads();
    if (tid < 12) {
        float m = -1e30f;
        for (int t = 0; t < 12; t++) m = fmaxf(m, sE[t * 12 + tid]);
        float s = 0.f;
        for (int t = 0; t < 12; t++) s += expf(sE[t * 12 + tid] - m);
        mx[tid] = m; sm[tid] = s;
    }
    __syncthreads();
    float val = 0.f;
    if (tid < 144) {
        int u = tid % 12;
        val = expf(sE[tid] - mx[u]) / sm[u];
        E[b * 144 + tid] = val;
    }
    __syncthreads();
    if (tid < 144) sE[tid] = val;
    __syncthreads();
    if (tid < 12) {
        float a = 0.f;
        for (int u = 0; u < 12; u++) a += sE[tid * 12 + u] * W1[u];
        EW1[b * 12 + tid] = a;
    }
}

// ---------------- l2/r2 from Xrow (bf16, packed loads) ----------------
__global__ __launch_bounds__(384) void k_l2r2x(const unsigned short* __restrict__ Xrow,
                                               const float* __restrict__ rr3,
                                               const float* __restrict__ E,
                                               const float* __restrict__ EW1,
                                               const float* __restrict__ W2,
                                               float* __restrict__ l2,
                                               float* __restrict__ r2)
{
    __shared__ float xs[8 * 384];
    __shared__ float Es[144], ew[12], rrs[96], lp[8][32];
    int b = blockIdx.y, tid = threadIdx.x;
    int n0 = blockIdx.x * 8;
    size_t r0 = (size_t)b * NN + n0;
    if (tid < 144) Es[tid] = E[b * 144 + tid];
    if (tid < 12) ew[tid] = EW1[b * 12 + tid];
    if (tid < 96) rrs[tid] = rr3[(r0 + tid / 12) * 12 + (tid % 12)];
    const unsigned int* Xr = (const unsigned int*)(Xrow + r0 * 384);
    for (int i2 = tid; i2 < 1536; i2 += 384) {
        unsigned int w = Xr[i2];
        xs[2 * i2]     = bf2f((unsigned short)(w & 0xffff));
        xs[2 * i2 + 1] = bf2f((unsigned short)(w >> 16));
    }
    __syncthreads();
    if (tid < 256) {
        int i = tid >> 5, f = tid & 31;
        float a = 0.f;
#pragma unroll
        for (int t = 0; t < 12; t++) a += xs[i * 384 + f * 12 + t] * ew[t];
        lp[i][f] = a;
    }
    __syncthreads();
    if (tid < 96) {
        int i = tid / 12, u = tid - i * 12;
        float a = 0.f;
        for (int f = 0; f < 32; f++) a += lp[i][f] * W2[f * 12 + u];
        l2[(r0 + i) * 12 + u] = a;
        float rv = 0.f;
#pragma unroll
        for (int t = 0; t < 12; t++) rv += rrs[i * 12 + t] * Es[t * 12 + u];
        r2[((size_t)b * 12 + u) * NN + n0 + i] = rv;
    }
}

// Xt[b][j][n] = Xrow[b][n][j]; flat blocks < 1024 also convert Vs row -> bf16
__global__ __launch_bounds__(256) void k_xt(const unsigned short* __restrict__ Xrow,
                                            unsigned short* __restrict__ Xt,
                                            const float* __restrict__ Vs,
                                            unsigned short* __restrict__ Vsb)
{
    int tid = threadIdx.x;
    int fid = blockIdx.x + 6 * (blockIdx.y + 16 * blockIdx.z);
    if (fid < 1024) {
        size_t i = (size_t)fid * 1024 + tid * 4;
        float4 v = *(const float4*)(Vs + i);
        unsigned int p0 = (unsigned int)cvt_bf(v.x) | ((unsigned int)cvt_bf(v.y) << 16);
        unsigned int p1 = (unsigned int)cvt_bf(v.z) | ((unsigned int)cvt_bf(v.w) << 16);
        *(unsigned int*)(Vsb + i) = p0;
        *(unsigned int*)(Vsb + i + 2) = p1;
    }
    __shared__ unsigned short tl[64][66];
    int b = blockIdx.z;
    int n0 = blockIdx.y * 64, j0 = blockIdx.x * 64;
    int c = tid & 63, r0 = tid >> 6;
    for (int i = 0; i < 16; i++) {
        int r = r0 + i * 4;
        tl[r][c] = Xrow[((size_t)b * NN + n0 + r) * 384 + j0 + c];
    }
    __syncthreads();
    int c2 = tid & 31, r4 = tid >> 5;
    unsigned short* ob = Xt + ((size_t)b * 384 + j0) * NN + n0;
    for (int i = 0; i < 8; i++) {
        int jr = r4 + i * 8;
        unsigned int v0 = (unsigned int)tl[2 * c2][jr] | ((unsigned int)tl[2 * c2 + 1][jr] << 16);
        *(unsigned int*)(ob + (size_t)jr * NN + 2 * c2) = v0;
    }
}

// ---------------- tiled P ----------------
__global__ __launch_bounds__(256) void k_Ptile(const float* __restrict__ l2,
                                               const float* __restrict__ r2,
                                               const float* __restrict__ bsin,
                                               unsigned short* __restrict__ Pt)
{
    __shared__ float l2s[64][13];
    __shared__ float r2s[12][64];
    __shared__ float bsS[64][65];
    int k0 = blockIdx.x * 64, m0 = blockIdx.y * 64, b = blockIdx.z;
    int tid = threadIdx.x;
    for (int i = tid; i < 768; i += 256) {
        int r = i / 12, t = i - r * 12;
        l2s[r][t] = l2[((size_t)b * NN + m0 + r) * 12 + t];
    }
    for (int i = tid; i < 768; i += 256) {
        int t = i >> 6, k = i & 63;
        r2s[t][k] = r2[((size_t)b * 12 + t) * NN + k0 + k];
    }
    for (int i = tid; i < 4096; i += 256) {
        int r = i >> 6, c = i & 63;
        bsS[r][c] = bsin[(size_t)(m0 + r) * NN + k0 + c];
    }
    __syncthreads();
    int m = tid & 63, kg = tid >> 6;
    float lv[12];
#pragma unroll
    for (int t = 0; t < 12; t++) lv[t] = l2s[m][t];
#pragma unroll
    for (int s = 0; s < 16; s++) {
        int kl = kg * 16 + s;
        float p = bsS[m][kl];
#pragma unroll
        for (int t = 0; t < 12; t++) p += lv[t] * r2s[t][kl];
        float sg = 1.f / (1.f + expf(-p));
        Pt[((size_t)b * NN + k0 + kl) * NN + m0 + m] = cvt_bf(sg);
    }
}

// bf16 transpose 1024x1024
__global__ __launch_bounds__(256) void k_tb16(const unsigned short* __restrict__ s,
                                              unsigned short* __restrict__ d)
{
    __shared__ unsigned short tl[64][65];
    int r0 = blockIdx.y * 64, c0 = blockIdx.x * 64;
    int tid = threadIdx.x;
    int c = tid & 63, rr = tid >> 6;
    for (int i = 0; i < 16; i++)
        tl[rr + i * 4][c] = s[(size_t)(r0 + rr + i * 4) * NN + c0 + c];
    __syncthreads();
    for (int i = 0; i < 16; i++)
        d[(size_t)(c0 + rr + i * 4) * NN + r0 + c] = tl[c][rr + i * 4];
}

// ---------------- 8-phase 256x256 S-GEMM: expB[b] = bf16(exp(Vs @ Pt[b]^T)) + colsum ----------------
__device__ inline void stage2(const short* __restrict__ g, int grow0, int gk0,
                              short* dstbase, int tid)
{
#pragma unroll
    for (int o = 0; o < 2; o++) {
        int y = o * 8192 + tid * 16;
        int rowh = y >> 7;
        int colb = (y & 127) ^ ((rowh & 7) << 4);
        const short* src = g + (size_t)(grow0 + rowh) * NN + gk0 + (colb >> 1);
        gll16(src, dstbase + (y >> 1));
    }
}

__global__ __launch_bounds__(512, 2) void sgemm8(const short* __restrict__ A,
                                                 const short* __restrict__ Bm,
                                                 unsigned short* __restrict__ expB,
                                                 float* __restrict__ colsum)
{
    int bz = blockIdx.z;
    const short* Bb = Bm + (size_t)bz * NN * NN;
    int i0 = blockIdx.y * 256, j0 = blockIdx.x * 256;
    __shared__ short sm[65536];
    int tid = threadIdx.x;
    int ln = tid & 63, wv = tid >> 6;
    int wm = (wv >> 2) * 128, wn = (wv & 3) * 64;
    int fr = ln & 15, fk = ln >> 4;
    int ahalf = wv >> 2;
    int bhalf = wn >> 7;
    int bcol = wn & 64;
    int swz = (fr & 7) << 4;
    int kcol0 = ((fk * 16) ^ swz) >> 1;
    int kcol1 = ((64 + fk * 16) ^ swz) >> 1;

    f32x4 acc[8][4];
#pragma unroll
    for (int m = 0; m < 8; m++)
#pragma unroll
        for (int n = 0; n < 4; n++) acc[m][n] = (f32x4)(0.f);

    stage2(Bb, j0 + 0,   0,  sm + 16384,        tid);
    stage2(Bb, j0 + 128, 0,  sm + 16384 + 8192, tid);
    stage2(A,  i0 + 0,   0,  sm + 0,            tid);
    stage2(A,  i0 + 128, 0,  sm + 8192,         tid);
    stage2(Bb, j0 + 0,   64, sm + 32768 + 16384,        tid);
    stage2(Bb, j0 + 128, 64, sm + 32768 + 16384 + 8192, tid);
    asm volatile("s_waitcnt vmcnt(4)" ::: "memory");
    __builtin_amdgcn_s_barrier();

    for (int i = 0; i < 8; i++) {
        bf16x8 bv[8];
#pragma unroll
        for (int ph = 0; ph < 8; ph++) {
            int t = 2 * i + (ph >> 2);
            int p = t & 1;
            int q = ph & 3;
            int abase = p * 32768 + ahalf * 8192;
            int bbase = p * 32768 + 16384 + bhalf * 8192;
            if (q == 0) {
#pragma unroll
                for (int nj = 0; nj < 4; nj++) {
                    int browh = bcol + nj * 16 + fr;
                    bv[nj * 2 + 0] = *(const bf16x8*)(sm + bbase + browh * 64 + kcol0);
                    bv[nj * 2 + 1] = *(const bf16x8*)(sm + bbase + browh * 64 + kcol1);
                }
            }
            bf16x8 av[4];
#pragma unroll
            for (int m2 = 0; m2 < 2; m2++) {
                int rowh = (2 * q + m2) * 16 + fr;
                av[m2 * 2 + 0] = *(const bf16x8*)(sm + abase + rowh * 64 + kcol0);
                av[m2 * 2 + 1] = *(const bf16x8*)(sm + abase + rowh * 64 + kcol1);
            }
            {
                int st, smat, shalf;
                if (ph == 0)      { st = 2 * i + 1; smat = 0; shalf = 0; }
                else if (ph == 1) { st = 2 * i + 1; smat = 0; shalf = 1; }
                else if (ph == 2) { st = 2 * i + 2; smat = 1; shalf = 0; }
                else if (ph == 3) { st = 2 * i + 2; smat = 1; shalf = 1; }
                else if (ph == 4) { st = 2 * i + 2; smat = 0; shalf = 0; }
                else if (ph == 5) { st = 2 * i + 2; smat = 0; shalf = 1; }
                else if (ph == 6) { st = 2 * i + 3; smat = 1; shalf = 0; }
                else              { st = 2 * i + 3; smat = 1; shalf = 1; }
                if (st < 16) {
                    short* dst = sm + (st & 1) * 32768 + smat * 16384 + shalf * 8192;
                    const short* g = smat ? Bb : A;
                    int grow0 = (smat ? j0 : i0) + shalf * 128;
                    stage2(g, grow0, st * 64, dst, tid);
                }
            }
            __builtin_amdgcn_s_barrier();
            __builtin_amdgcn_s_setprio(1);
#pragma unroll
            for (int m2 = 0; m2 < 2; m2++)
#pragma unroll
                for (int nj = 0; nj < 4; nj++) {
                    acc[2 * q + m2][nj] = __builtin_amdgcn_mfma_f32_16x16x32_bf16(
                        av[m2 * 2 + 0], bv[nj * 2 + 0], acc[2 * q + m2][nj], 0, 0, 0);
                    acc[2 * q + m2][nj] = __builtin_amdgcn_mfma_f32_16x16x32_bf16(
                        av[m2 * 2 + 1], bv[nj * 2 + 1], acc[2 * q + m2][nj], 0, 0, 0);
                }
            __builtin_amdgcn_s_setprio(0);
            if (ph == 3 || ph == 7) {
                if (i < 7) asm volatile("s_waitcnt vmcnt(4)" ::: "memory");
                else       asm volatile("s_waitcnt vmcnt(0)" ::: "memory");
            }
            __builtin_amdgcn_s_barrier();
        }
    }
    unsigned short* Cb = expB + (size_t)bz * NN * NN;
#pragma unroll
    for (int nj = 0; nj < 4; nj++) {
        int col = j0 + wn + nj * 16 + fr;
        float cs = 0.f;
#pragma unroll
        for (int m = 0; m < 8; m++) {
            int row = i0 + wm + m * 16 + fk * 4;
#pragma unroll
            for (int r = 0; r < 4; r++) {
                float e = expf(acc[m][nj][r]);
                Cb[(size_t)(row + r) * NN + col] = cvt_bf(e);
                cs += e;
            }
        }
        cs += __shfl_xor(cs, 16);
        cs += __shfl_xor(cs, 32);
        if (ln < 16) atomicAdd(&colsum[(size_t)bz * NN + col], cs);
    }
}

// ---------------- MFMA bf16 NT GEMM (MODE 3: split-K fp32 atomicAdd) ----------------
template<int MODE>
__global__ __launch_bounds__(256) void mgemm(const short* __restrict__ A,
                                             const short* __restrict__ B,
                                             void* __restrict__ Cv,
                                             int Kd, int kchunk,
                                             int ldA, int ldB, int ldC,
                                             long sA, long sB, long sC,
                                             float* __restrict__ colsum)
{
    int bz = blockIdx.z;
    const short* Ab = A + (size_t)bz * sA;
    const short* Bb = B + (size_t)bz * sB;
    int i0 = blockIdx.y * 128, j0 = blockIdx.x * 128;
    __shared__ short sm[16384];
    int tid = threadIdx.x;
    int ln = tid & 63, wv = tid >> 6;
    int wm = (wv >> 1) * 64, wn = (wv & 1) * 64;
    int fr = ln & 15, fk = ln >> 4;
    f32x4 acc[4][4];
#pragma unroll
    for (int a = 0; a < 4; a++)
#pragma unroll
        for (int b2 = 0; b2 < 4; b2++) acc[a][b2] = (f32x4)(0.f);

    int k_lo = 0, k_hi = Kd;
    if constexpr (MODE == 3) { k_lo = bz * kchunk; k_hi = k_lo + kchunk; }

    for (int k0 = k_lo; k0 < k_hi; k0 += 64) {
#pragma unroll
        for (int q = 0; q < 4; q++) {
            int e = q * 2048 + tid * 8;
            const short* src = Ab + (size_t)(i0 + (e >> 6)) * ldA + k0 + (e & 63);
            gll16(src, sm + e);
        }
#pragma unroll
        for (int q = 0; q < 4; q++) {
            int e = q * 2048 + tid * 8;
            const short* src = Bb + (size_t)(j0 + (e >> 6)) * ldB + k0 + (e & 63);
            gll16(src, sm + 8192 + e);
        }
        __syncthreads();
#pragma unroll
        for (int ks = 0; ks < 2; ks++) {
            bf16x8 av[4], bv[4];
#pragma unroll
            for (int mi = 0; mi < 4; mi++)
                av[mi] = *(const bf16x8*)(sm + (wm + mi * 16 + fr) * 64 + ks * 32 + fk * 8);
#pragma unroll
            for (int nj = 0; nj < 4; nj++)
                bv[nj] = *(const bf16x8*)(sm + 8192 + (wn + nj * 16 + fr) * 64 + ks * 32 + fk * 8);
#pragma unroll
            for (int mi = 0; mi < 4; mi++)
#pragma unroll
                for (int nj = 0; nj < 4; nj++)
                    acc[mi][nj] = __builtin_amdgcn_mfma_f32_16x16x32_bf16(av[mi], bv[nj], acc[mi][nj], 0, 0, 0);
        }
        __syncthreads();
    }
    if constexpr (MODE == 3) {
        float* Cb = (float*)Cv;
#pragma unroll
        for (int mi = 0; mi < 4; mi++)
#pragma unroll
            for (int nj = 0; nj < 4; nj++) {
                int row = i0 + wm + mi * 16 + fk * 4;
                int col = j0 + wn + nj * 16 + fr;
#pragma unroll
                for (int r = 0; r < 4; r++)
                    atomicAdd(&Cb[(size_t)(row + r) * ldC + col], acc[mi][nj][r]);
            }
    }
}

// ---------------- merged h-GEMMs: 768 blocks ----------------
__global__ __launch_bounds__(256) void mgemm_hh(const short* __restrict__ A1,
                                                const short* __restrict__ A2,
                                                const short* __restrict__ B,
                                                unsigned short* __restrict__ C1,
                                                unsigned short* __restrict__ C2)
{
    int id = blockIdx.x;
    int half = id / 384;
    int sid = id - half * 384;
    int xcd = sid & 7, jj = sid >> 3;
    int b = (xcd << 1) | (jj / 24);
    int r = jj % 24;
    int i0 = (r / 3) * 128, j0 = (r % 3) * 128;
    const short* Ab = (half ? A2 : A1) + (size_t)b * NN * NN;
    const short* Bb = B + (size_t)b * 384 * NN;
    unsigned short* C = half ? C2 : C1;
    __shared__ short sm[16384];
    int tid = threadIdx.x;
    int ln = tid & 63, wv = tid >> 6;
    int wm = (wv >> 1) * 64, wn = (wv & 1) * 64;
    int fr = ln & 15, fk = ln >> 4;
    f32x4 acc[4][4];
#pragma unroll
    for (int a = 0; a < 4; a++)
#pragma unroll
        for (int b2 = 0; b2 < 4; b2++) acc[a][b2] = (f32x4)(0.f);

    for (int k0 = 0; k0 < NN; k0 += 64) {
#pragma unroll
        for (int q = 0; q < 4; q++) {
            int e = q * 2048 + tid * 8;
            gll16(Ab + (size_t)(i0 + (e >> 6)) * NN + k0 + (e & 63), sm + e);
        }
#pragma unroll
        for (int q = 0; q < 4; q++) {
            int e = q * 2048 + tid * 8;
            gll16(Bb + (size_t)(j0 + (e >> 6)) * NN + k0 + (e & 63), sm + 8192 + e);
        }
        __syncthreads();
#pragma unroll
        for (int ks = 0; ks < 2; ks++) {
            bf16x8 av[4], bv[4];
#pragma unroll
            for (int mi = 0; mi < 4; mi++)
                av[mi] = *(const bf16x8*)(sm + (wm + mi * 16 + fr) * 64 + ks * 32 + fk * 8);
#pragma unroll
            for (int nj = 0; nj < 4; nj++)
                bv[nj] = *(const bf16x8*)(sm + 8192 + (wn + nj * 16 + fr) * 64 + ks * 32 + fk * 8);
#pragma unroll
            for (int mi = 0; mi < 4; mi++)
#pragma unroll
                for (int nj = 0; nj < 4; nj++)
                    acc[mi][nj] = __builtin_amdgcn_mfma_f32_16x16x32_bf16(av[mi], bv[nj], acc[mi][nj], 0, 0, 0);
        }
        __syncthreads();
    }
#pragma unroll
    for (int mi = 0; mi < 4; mi++)
#pragma unroll
        for (int nj = 0; nj < 4; nj++) {
            int row = i0 + wm + mi * 16 + fk * 4;
            int col = j0 + wn + nj * 16 + fr;
#pragma unroll
            for (int r2 = 0; r2 < 4; r2++)
                C[((size_t)b * NN + row + r2) * 384 + col] = cvt_bf(acc[mi][nj][r2]);
        }
}

// ---------------- normalize + threshold + At1 + At2 + sdiag (reads bf16 expB, b-fastest grid) ----------------
__global__ __launch_bounds__(256) void k_normprep2(const unsigned short* __restrict__ expB,
                                                   float* __restrict__ spat,
                                                   const float* __restrict__ colsum,
                                                   const float* __restrict__ sup,
                                                   const float* __restrict__ supsq,
                                                   unsigned short* __restrict__ At1,
                                                   unsigned short* __restrict__ At2,
                                                   float* __restrict__ sdiag)
{
    __shared__ unsigned short t1[64][66];
    __shared__ unsigned short t2[64][66];
    int b = blockIdx.x;
    int m0 = blockIdx.y * 64, n0 = blockIdx.z * 64;
    int tid = threadIdx.x;
    int c = tid & 63, r0 = tid >> 6;
    const float thr = (1.0f / 1024.0f) / 0.6f;
    float inv = 1.f / colsum[(size_t)b * NN + m0 + c];
    const unsigned short* eb = expB + (size_t)b * NN * NN;
    float* sp = spat + (size_t)b * NN * NN;
    for (int i = 0; i < 16; i++) {
        int r = r0 + i * 4;
        size_t idx = (size_t)(n0 + r) * NN + m0 + c;
        float v = bf2f(eb[idx]) * inv;
        v = (v < thr) ? 0.f : v;
        sp[idx] = v;
        if (n0 + r == m0 + c) sdiag[(size_t)b * NN + n0 + r] = v;
        t1[r][c] = cvt_bf(sup[(size_t)(n0 + r) * NN + m0 + c] * v);
        float p2 = 2.f * supsq[(size_t)(n0 + r) * NN + m0 + c]
                 - (((n0 + r) == (m0 + c)) ? 1.f : 0.f);
        t2[r][c] = cvt_bf(p2 * v);
    }
    __syncthreads();
    int c2 = tid & 31, r4 = tid >> 5;
    size_t ob = ((size_t)b * NN + m0) * NN + n0;
    for (int i = 0; i < 8; i++) {
        int rr = r4 + i * 8;
        unsigned int v1 = (unsigned int)t1[2 * c2][rr] | ((unsigned int)t1[2 * c2 + 1][rr] << 16);
        unsigned int v2 = (unsigned int)t2[2 * c2][rr] | ((unsigned int)t2[2 * c2 + 1][rr] << 16);
        *(unsigned int*)(At1 + ob + (size_t)rr * NN + 2 * c2) = v1;
        *(unsigned int*)(At2 + ob + (size_t)rr * NN + 2 * c2) = v2;
    }
}

// ---------------- support graph ----------------
__global__ __launch_bounds__(256) void k_sup(const float* __restrict__ emb,
                                             float* __restrict__ sup,
                                             unsigned short* __restrict__ supB)
{
    int n = blockIdx.x, tid = threadIdx.x;
    __shared__ float en[16];
    if (tid < 16) en[tid] = emb[n * 16 + tid];
    __syncthreads();
    float v[4];
#pragma unroll
    for (int q = 0; q < 4; q++) {
        int m = q * 256 + tid;
        float d = 0.f;
#pragma unroll
        for (int dd = 0; dd < 16; dd++) d += en[dd] * emb[m * 16 + dd];
        v[q] = fmaxf(d, 0.f);
    }
    float mx = fmaxf(fmaxf(v[0], v[1]), fmaxf(v[2], v[3]));
    for (int o = 32; o > 0; o >>= 1) mx = fmaxf(mx, __shfl_xor(mx, o));
    __shared__ float red[4];
    if ((tid & 63) == 0) red[tid >> 6] = mx;
    __syncthreads();
    mx = fmaxf(fmaxf(red[0], red[1]), fmaxf(red[2], red[3]));
    float e[4];
    float s = 0.f;
#pragma unroll
    for (int q = 0; q < 4; q++) { e[q] = expf(v[q] - mx); s += e[q]; }
    for (int o = 32; o > 0; o >>= 1) s += __shfl_xor(s, o);
    __shared__ float red2[4];
    if ((tid & 63) == 0) red2[tid >> 6] = s;
    __syncthreads();
    s = red2[0] + red2[1] + red2[2] + red2[3];
    float inv = 1.f / s;
#pragma unroll
    for (int q = 0; q < 4; q++) {
        float val = e[q] * inv;
        sup[(size_t)n * NN + q * 256 + tid] = val;
        supB[(size_t)n * NN + q * 256 + tid] = cvt_bf(val);
    }
}

// ---------------- merged weight prep ----------------
__global__ __launch_bounds__(256) void k_wprep(const float* __restrict__ tcv,
                                               const float* __restrict__ tcg,
                                               const float* __restrict__ Theta,
                                               const float* __restrict__ rcw,
                                               unsigned short* __restrict__ Wr,
                                               unsigned short* __restrict__ Th,
                                               unsigned short* __restrict__ Rc)
{
    int tid = threadIdx.x;
    if (blockIdx.x < 64) {
        int o = blockIdx.x;
        float t = 0.f, p = 0.f;
        if (tid < 192) { t = tcv[o * 192 + tid]; p = t * t; }
        for (int off = 32; off > 0; off >>= 1) p += __shfl_xor(p, off);
        __shared__ float wsr[3];
        if (tid < 192 && (tid & 63) == 0) wsr[tid >> 6] = p;
        __syncthreads();
        if (tid < 192) {
            float sum = wsr[0] + wsr[1] + wsr[2];
            int c = tid / 3, dt = tid - c * 3;
            Wr[o * 192 + dt * 64 + c] = cvt_bf(t * (tcg[o] / sqrtf(sum)));
        }
    } else {
        for (int i = tid; i < 6144; i += 256) {
            int o = i / 96, rem = i - o * 96;
            int kind = rem >> 5, f = rem & 31;
            Th[i] = cvt_bf(Theta[kind * 2048 + f * 64 + o]);
        }
        for (int i = tid; i < 2048; i += 256) Rc[i] = cvt_bf(rcw[i]);
    }
}

// ---------------- MFMA fused tail (reads Xrow bf16) ----------------
__global__ __launch_bounds__(256) void k_tail(const unsigned short* __restrict__ Xrow,
                                              const unsigned short* __restrict__ h1,
                                              const unsigned short* __restrict__ h2,
                                              const float* __restrict__ sdiag,
                                              const unsigned short* __restrict__ Th,
                                              const unsigned short* __restrict__ Wr,
                                              const unsigned short* __restrict__ Rc,
                                              const float* __restrict__ tcb,
                                              const float* __restrict__ rcb,
                                              const float* __restrict__ lnw,
                                              const float* __restrict__ lnb,
                                              float* __restrict__ out)
{
    int b = blockIdx.y;
    int node0 = blockIdx.x * 4;
    int tid = threadIdx.x;
    int ln = tid & 63, wv = tid >> 6;
    int fr = ln & 15, fk = ln >> 4;

    __shared__ union {
        struct { unsigned short xt[1920], h1t[1920], h2t[1920], gcn[4032]; } a;
        float Y[48 * 65];
    } u;
    __shared__ float sdp[48];
    __shared__ float lnwS[64], lnbS[64], tbS[64];
    __shared__ float muS[48], rsS[48];

    size_t rowb = ((size_t)b * NN + node0) * 384;
    {
        const unsigned int* xp = (const unsigned int*)(Xrow + rowb);
        const unsigned int* h1p = (const unsigned int*)(h1 + rowb);
        const unsigned int* h2p = (const unsigned int*)(h2 + rowb);
        for (int q = tid; q < 768; q += 256) {
            int j0 = q * 2;
            int node = j0 / 384, j = j0 - node * 384;
            int f = j / 12, t = j - f * 12;
            int t2 = t + 1, f2 = f;
            if (t2 == 12) { t2 = 0; f2 = f + 1; }
            int la0 = node * 480 + t * 40 + f;
            int la1 = node * 480 + t2 * 40 + f2;
            unsigned int wx = xp[q], w1 = h1p[q], w2 = h2p[q];
            u.a.xt[la0] = (unsigned short)(wx & 0xffff); u.a.xt[la1] = (unsigned short)(wx >> 16);
            u.a.h1t[la0] = (unsigned short)(w1 & 0xffff); u.a.h1t[la1] = (unsigned short)(w1 >> 16);
            u.a.h2t[la0] = (unsigned short)(w2 & 0xffff); u.a.h2t[la1] = (unsigned short)(w2 >> 16);
        }
    }
    for (int i = tid; i < 576; i += 256) {
        int node = i / 144, r = i - node * 144;
        int rr = (r < 72) ? 0 : 13;
        u.a.gcn[node * 1008 + rr * 72 + (r % 72)] = 0;
    }
    if (tid < 48) sdp[tid] = sdiag[(size_t)b * NN + node0 + tid / 12];
    if (tid < 64) { lnwS[tid] = lnw[tid]; lnbS[tid] = lnb[tid]; tbS[tid] = tcb[tid] + rcb[tid]; }

    int ocol = wv * 16 + fr;
    bf16x8 bTh[3], bWr[6], bRc;
#pragma unroll
    for (int kb = 0; kb < 3; kb++)
        bTh[kb] = *(const bf16x8*)((const short*)Th + (size_t)ocol * 96 + kb * 32 + fk * 8);
#pragma unroll
    for (int kb = 0; kb < 6; kb++)
        bWr[kb] = *(const bf16x8*)((const short*)Wr + (size_t)ocol * 192 + kb * 32 + fk * 8);
    bRc = *(const bf16x8*)((const short*)Rc + (size_t)ocol * 32 + fk * 8);

    int na[3], ta[3];
#pragma unroll
    for (int rb = 0; rb < 3; rb++) {
        int p = rb * 16 + fr;
        na[rb] = p / 12; ta[rb] = p - na[rb] * 12;
    }
    __syncthreads();

    f32x4 acc[3];
#pragma unroll
    for (int rb = 0; rb < 3; rb++) {
        int ax = na[rb] * 480 + ta[rb] * 40 + fk * 8;
        bf16x8 avx = *(const bf16x8*)(u.a.xt + ax);
        f32x4 z = (f32x4)(0.f);
        acc[rb] = __builtin_amdgcn_mfma_f32_16x16x32_bf16(avx, bTh[0], z, 0, 0, 0);
#pragma unroll
        for (int r = 0; r < 4; r++) acc[rb][r] *= sdp[rb * 16 + fk * 4 + r];
        bf16x8 av1 = *(const bf16x8*)(u.a.h1t + ax);
        acc[rb] = __builtin_amdgcn_mfma_f32_16x16x32_bf16(av1, bTh[1], acc[rb], 0, 0, 0);
        bf16x8 av2 = *(const bf16x8*)(u.a.h2t + ax);
        acc[rb] = __builtin_amdgcn_mfma_f32_16x16x32_bf16(av2, bTh[2], acc[rb], 0, 0, 0);
    }
#pragma unroll
    for (int rb = 0; rb < 3; rb++) {
#pragma unroll
        for (int r = 0; r < 4; r++) {
            int pc = rb * 16 + fk * 4 + r;
            int nc = pc / 12, tc2 = pc - nc * 12;
            u.a.gcn[nc * 1008 + (tc2 + 1) * 72 + wv * 16 + fr] = cvt_bf(fmaxf(acc[rb][r], 0.f));
        }
    }
    __syncthreads();
#pragma unroll
    for (int rb = 0; rb < 3; rb++) {
        f32x4 a2 = (f32x4)(0.f);
#pragma unroll
        for (int kb = 0; kb < 6; kb++) {
            int dt = kb >> 1, c0 = (kb & 1) * 32;
            bf16x8 ag = *(const bf16x8*)(u.a.gcn + na[rb] * 1008 + (ta[rb] + dt) * 72 + c0 + fk * 8);
            a2 = __builtin_amdgcn_mfma_f32_16x16x32_bf16(ag, bWr[kb], a2, 0, 0, 0);
        }
        int ax = na[rb] * 480 + ta[rb] * 40 + fk * 8;
        bf16x8 avx = *(const bf16x8*)(u.a.xt + ax);
        acc[rb] = __builtin_amdgcn_mfma_f32_16x16x32_bf16(avx, bRc, a2, 0, 0, 0);
    }
    __syncthreads();
    float tb = tbS[ocol];
#pragma unroll
    for (int rb = 0; rb < 3; rb++)
#pragma unroll
        for (int r = 0; r < 4; r++)
            u.Y[(rb * 16 + fk * 4 + r) * 65 + ocol] = acc[rb][r] + tb;
    __syncthreads();
    if (tid < 48) {
        float s = 0.f, s2 = 0.f;
        for (int o = 0; o < 64; o++) {
            float v = u.Y[tid * 65 + o];
            s += v; s2 += v * v;
        }
        float mm = s * (1.f / 64.f);
        float var = s2 * (1.f / 64.f) - mm * mm;
        muS[tid] = mm; rsS[tid] = rsqrtf(var + 1e-5f);
    }
    __syncthreads();
    float2* obv = (float2*)(out + rowb * 2);
    for (int q = tid; q < 1536; q += 256) {
        int i = q * 2;
        int node = i / 768, rr = i - node * 768;
        int o = rr / 12, t = rr - o * 12;
        int p0 = node * 12 + t;
        float v0 = (u.Y[p0 * 65 + o] - muS[p0]) * rsS[p0] * lnwS[o] + lnbS[o];
        int t1 = t + 1, o1 = o;
        if (t1 == 12) { t1 = 0; o1 = o + 1; }
        int p1 = node * 12 + t1;
        float v1 = (u.Y[p1 * 65 + o1] - muS[p1]) * rsS[p1] * lnwS[o1] + lnbS[o1];
        float2 pk; pk.x = v0; pk.y = v1;
        obv[q] = pk;
    }
}

extern "C" void kernel_launch(void* const* d_in, const int* in_sizes, int n_in,
                              void* d_out, int out_size, void* d_ws, size_t ws_size,
                              hipStream_t stream)
{
    const float* x    = (const float*)d_in[0];
    const float* emb  = (const float*)d_in[1];
    const float* W1   = (const float*)d_in[2];
    const float* W2   = (const float*)d_in[3];
    const float* W3   = (const float*)d_in[4];
    const float* bs   = (const float*)d_in[5];
    const float* Vs   = (const float*)d_in[6];
    const float* U1   = (const float*)d_in[7];
    const float* U2   = (const float*)d_in[8];
    const float* U3   = (const float*)d_in[9];
    const float* be   = (const float*)d_in[10];
    const float* Ve   = (const float*)d_in[11];
    const float* Theta= (const float*)d_in[12];
    const float* tcv  = (const float*)d_in[13];
    const float* tcg  = (const float*)d_in[14];
    const float* tcb  = (const float*)d_in[15];
    const float* rcw  = (const float*)d_in[16];
    const float* rcb  = (const float*)d_in[17];
    const float* lnw  = (const float*)d_in[18];
    const float* lnb  = (const float*)d_in[19];

    float* xres = (float*)d_out;                       // B*N*FT*T fp32 (scratch for At2 until k_tail)
    float* spat = xres + (size_t)NB * NN * NFT * NT;   // B*N*N fp32

    char* base = (char*)d_ws;                          // ws >= 448 MiB; non-overlapping layout
    unsigned short* Xrow = (unsigned short*)(base + 0);            // 12.6 MB, live -> k_tail
    unsigned short* Pt   = (unsigned short*)(base + 16777216);     // 33.5 MB
    unsigned short* expB = (unsigned short*)(base + 56623104);     // 33.5 MB
    unsigned short* At1  = (unsigned short*)(base + 96468992);     // 33.5 MB
    unsigned short* At2  = (unsigned short*)xres;                  // d_out scratch (33.5 < 50.3 MB)
    unsigned short* Xt   = (unsigned short*)(base + 134217728);    // 12.6 MB
    unsigned short* h1   = (unsigned short*)(base + 150994944);    // 12.6 MB
    unsigned short* h2   = (unsigned short*)(base + 167772160);    // 12.6 MB
    unsigned short* Vsb  = (unsigned short*)(base + 184549376);    // 2 MB
    float* colsum  = (float*)(base + 188743680);
    float* sdiag   = (float*)(base + 188809216);
    float* sup     = (float*)(base + 192937984);
    unsigned short* supB = (unsigned short*)(base + 197132288);
    unsigned short* supT = (unsigned short*)(base + 199229440);
    float* supsq   = (float*)(base + 201326592);
    float* lhs_pre = (float*)(base + 205520896);
    float* M2      = (float*)(base + 205545472);
    float* rhs     = (float*)(base + 205570048);
    float* rr3     = (float*)(base + 206356480);
    float* E       = (float*)(base + 207142912);
    float* EW1     = (float*)(base + 207152128);
    float* l2      = (float*)(base + 207153152);
    float* r2      = (float*)(base + 207939584);
    unsigned short* Wr = (unsigned short*)(base + 208726016);
    unsigned short* Th = (unsigned short*)(base + 208750592);
    unsigned short* Rc = (unsigned short*)(base + 208762880);

    hipMemsetAsync(lhs_pre, 0, 49152, stream);             // lhs_pre + M2 (contiguous)
    hipMemsetAsync(supsq, 0, (size_t)NN * NN * sizeof(float), stream);

    // pre-pass: x fp32 -> lhs_pre, rhs, rr3, Xrow(bf16)
    k_pre<<<dim3(16, 16), 384, 0, stream>>>(x, U1, U3, W3, lhs_pre, rhs, rr3, Xrow);
    k_M2<<<dim3(16, 32), 384, 0, stream>>>(U2, rhs, M2);
    k_E<<<16, 192, 0, stream>>>(lhs_pre, M2, be, Ve, W1, E, EW1);
    // spatial attention
    k_l2r2x<<<dim3(128, 16), 384, 0, stream>>>(Xrow, rr3, E, EW1, W2, l2, r2);
    k_xt<<<dim3(6, 16, 16), 256, 0, stream>>>(Xrow, Xt, Vs, Vsb);
    k_Ptile<<<dim3(16, 16, 16), 256, 0, stream>>>(l2, r2, bs, Pt);
    hipMemsetAsync(colsum, 0, (size_t)NB * NN * sizeof(float), stream);
    // 8-phase 256^2 S-GEMM: exp stored bf16 + colsum
    sgemm8<<<dim3(4, 4, 16), 512, 0, stream>>>((const short*)Vsb, (const short*)Pt,
                                               expB, colsum);
    // graph supports
    k_sup<<<1024, 256, 0, stream>>>(emb, sup, supB);
    k_tb16<<<dim3(16, 16), 256, 0, stream>>>(supB, supT);
    mgemm<3><<<dim3(8, 8, 4), 256, 0, stream>>>((const short*)supB, (const short*)supT,
        (void*)supsq, NN, 256, NN, NN, NN, 0L, 0L, 0L, nullptr);
    // normalize + threshold + masked adjacencies + diagonal (b-fastest grid)
    k_normprep2<<<dim3(16, 16, 16), 256, 0, stream>>>(expB, spat, colsum, sup, supsq,
                                                      At1, At2, sdiag);
    // merged h-GEMMs
    mgemm_hh<<<768, 256, 0, stream>>>((const short*)At1, (const short*)At2,
                                      (const short*)Xt, h1, h2);
    // tail
    k_wprep<<<65, 256, 0, stream>>>(tcv, tcg, Theta, rcw, Wr, Th, Rc);
    k_tail<<<dim3(256, 16), 256, 0, stream>>>(Xrow, h1, h2, sdiag, Th, Wr, Rc,
                                              tcb, rcb, lnw, lnb, xres);
}

// Round 13
// 297.653 us; speedup vs baseline: 1.0217x; 1.0217x over previous
//
#include <hip/hip_runtime.h>
#include <math.h>

#define NB 16      // B
#define NN 1024    // N
#define NF 32      // F
#define NT 12      // T
#define NFC 64
#define NFT 64

typedef __attribute__((ext_vector_type(8))) short bf16x8;
typedef __attribute__((ext_vector_type(4))) float f32x4;

__device__ inline unsigned short cvt_bf(float f) {
    unsigned int u = __float_as_uint(f);
    u += 0x7fff + ((u >> 16) & 1);
    return (unsigned short)(u >> 16);
}
__device__ inline float bf2f(unsigned short u) {
    return __uint_as_float(((unsigned int)u) << 16);
}
__device__ inline void gll16(const short* g, short* l) {
    __builtin_amdgcn_global_load_lds((const __attribute__((address_space(1))) void*)g,
                                     (__attribute__((address_space(3))) void*)l, 16, 0, 0);
}

// ---------------- fused pre-pass: lhs_pre (U1), rhs (U3), rr3 (W3), Xrow (bf16) ----------------
__global__ __launch_bounds__(384) void k_pre(const float* __restrict__ x,
                                             const float* __restrict__ U1,
                                             const float* __restrict__ U3,
                                             const float* __restrict__ W3,
                                             float* __restrict__ lhs_pre,
                                             float* __restrict__ rhs,
                                             float* __restrict__ rr3,
                                             unsigned short* __restrict__ Xrow)
{
    __shared__ float xs[8 * 384];
    int b = blockIdx.x, ch = blockIdx.y, tid = threadIdx.x;
    float acc = 0.f;
    for (int c8 = 0; c8 < 8; c8++) {
        int n0 = ch * 64 + c8 * 8;
        size_t r0 = (size_t)b * NN + n0;
        __syncthreads();
        for (int i = 0; i < 8; i++) xs[i * 384 + tid] = x[(r0 + i) * 384 + tid];
        __syncthreads();
        for (int i = 0; i < 8; i++) acc += xs[i * 384 + tid] * U1[n0 + i];
        for (int idx = tid; idx < 1536; idx += 384) {
            int row = idx / 192, jj = (idx - row * 192) * 2;
            unsigned int w = (unsigned int)cvt_bf(xs[row * 384 + jj])
                           | ((unsigned int)cvt_bf(xs[row * 384 + jj + 1]) << 16);
            *(unsigned int*)(Xrow + (r0 + row) * 384 + jj) = w;
        }
        if (tid < 192) {
            int half = tid / 96;
            int r = tid - half * 96;
            int i = r / 12, t = r - i * 12;
            const float* wv = half ? W3 : U3;
            float s = 0.f;
            for (int f = 0; f < 32; f++) s += wv[f] * xs[i * 384 + f * 12 + t];
            float* outp = half ? rr3 : rhs;
            outp[(r0 + i) * 12 + t] = s;
        }
    }
    int f = tid / 12, t = tid - f * 12;
    atomicAdd(&lhs_pre[b * 384 + t * 32 + f], acc);
}

// M2[b][f][u] = sum_n U2[f][n] * rhs[b][n][u]
__global__ __launch_bounds__(384) void k_M2(const float* __restrict__ U2,
                                            const float* __restrict__ rhs,
                                            float* __restrict__ M2)
{
    int b = blockIdx.x, ch = blockIdx.y, tid = threadIdx.x;
    int f = tid / 12, u = tid - (tid / 12) * 12;
    int n0 = ch * 32;
    float a = 0.f;
    for (int n = n0; n < n0 + 32; n++)
        a += U2[(size_t)f * NN + n] * rhs[((size_t)b * NN + n) * 12 + u];
    atomicAdd(&M2[b * 384 + f * 12 + u], a);
}

// E (softmax over t) + EW1; prod inline
__global__ __launch_bounds__(192) void k_E(const float* __restrict__ lhs_pre,
                                           const float* __restrict__ M2,
                                           const float* __restrict__ be,
                                           const float* __restrict__ Ve,
                                           const float* __restrict__ W1,
                                           float* __restrict__ E,
                                           float* __restrict__ EW1)
{
    int b = blockIdx.x, tid = threadIdx.x;
    __shared__ float lp2[384], m2s[384];
    __shared__ float ssig[144], sE[144], mx[12], sm[12];
    for (int i = tid; i < 384; i += 192) {
        lp2[i] = lhs_pre[b * 384 + i];
        m2s[i] = M2[b * 384 + i];
    }
    __syncthreads();
    if (tid < 144) {
        int s = tid / 12, u = tid - s * 12;
        float p = 0.f;
#pragma unroll
        for (int f = 0; f < 32; f++) p += lp2[s * 32 + f] * m2s[f * 12 + u];
        ssig[tid] = 1.f / (1.f + expf(-(p + be[tid])));
    }
    __syncthreads();
    if (tid < 144) {
        int t = tid / 12, u = tid - t * 12;
        float a = 0.f;
        for (int s2 = 0; s2 < 12; s2++) a += Ve[t * 12 + s2] * ssig[s2 * 12 + u];
        sE[tid] = a;
    }
    __syncthreads();
    if (tid < 12) {
        float m = -1e30f;
        for (int t = 0; t < 12; t++) m = fmaxf(m, sE[t * 12 + tid]);
        float s = 0.f;
        for (int t = 0; t < 12; t++) s += expf(sE[t * 12 + tid] - m);
        mx[tid] = m; sm[tid] = s;
    }
    __syncthreads();
    float val = 0.f;
    if (tid < 144) {
        int u = tid % 12;
        val = expf(sE[tid] - mx[u]) / sm[u];
        E[b * 144 + tid] = val;
    }
    __syncthreads();
    if (tid < 144) sE[tid] = val;
    __syncthreads();
    if (tid < 12) {
        float a = 0.f;
        for (int u = 0; u < 12; u++) a += sE[tid * 12 + u] * W1[u];
        EW1[b * 12 + tid] = a;
    }
}

// ---------------- l2/r2 from Xrow (bf16, packed loads) ----------------
__global__ __launch_bounds__(384) void k_l2r2x(const unsigned short* __restrict__ Xrow,
                                               const float* __restrict__ rr3,
                                               const float* __restrict__ E,
                                               const float* __restrict__ EW1,
                                               const float* __restrict__ W2,
                                               float* __restrict__ l2,
                                               float* __restrict__ r2)
{
    __shared__ float xs[8 * 384];
    __shared__ float Es[144], ew[12], rrs[96], lp[8][32];
    int b = blockIdx.y, tid = threadIdx.x;
    int n0 = blockIdx.x * 8;
    size_t r0 = (size_t)b * NN + n0;
    if (tid < 144) Es[tid] = E[b * 144 + tid];
    if (tid < 12) ew[tid] = EW1[b * 12 + tid];
    if (tid < 96) rrs[tid] = rr3[(r0 + tid / 12) * 12 + (tid % 12)];
    const unsigned int* Xr = (const unsigned int*)(Xrow + r0 * 384);
    for (int i2 = tid; i2 < 1536; i2 += 384) {
        unsigned int w = Xr[i2];
        xs[2 * i2]     = bf2f((unsigned short)(w & 0xffff));
        xs[2 * i2 + 1] = bf2f((unsigned short)(w >> 16));
    }
    __syncthreads();
    if (tid < 256) {
        int i = tid >> 5, f = tid & 31;
        float a = 0.f;
#pragma unroll
        for (int t = 0; t < 12; t++) a += xs[i * 384 + f * 12 + t] * ew[t];
        lp[i][f] = a;
    }
    __syncthreads();
    if (tid < 96) {
        int i = tid / 12, u = tid - i * 12;
        float a = 0.f;
        for (int f = 0; f < 32; f++) a += lp[i][f] * W2[f * 12 + u];
        l2[(r0 + i) * 12 + u] = a;
        float rv = 0.f;
#pragma unroll
        for (int t = 0; t < 12; t++) rv += rrs[i * 12 + t] * Es[t * 12 + u];
        r2[((size_t)b * 12 + u) * NN + n0 + i] = rv;
    }
}

// Xt[b][j][n] = Xrow[b][n][j]; flat blocks < 1024 also convert Vs row -> bf16
__global__ __launch_bounds__(256) void k_xt(const unsigned short* __restrict__ Xrow,
                                            unsigned short* __restrict__ Xt,
                                            const float* __restrict__ Vs,
                                            unsigned short* __restrict__ Vsb)
{
    int tid = threadIdx.x;
    int fid = blockIdx.x + 6 * (blockIdx.y + 16 * blockIdx.z);
    if (fid < 1024) {
        size_t i = (size_t)fid * 1024 + tid * 4;
        float4 v = *(const float4*)(Vs + i);
        unsigned int p0 = (unsigned int)cvt_bf(v.x) | ((unsigned int)cvt_bf(v.y) << 16);
        unsigned int p1 = (unsigned int)cvt_bf(v.z) | ((unsigned int)cvt_bf(v.w) << 16);
        *(unsigned int*)(Vsb + i) = p0;
        *(unsigned int*)(Vsb + i + 2) = p1;
    }
    __shared__ unsigned short tl[64][66];
    int b = blockIdx.z;
    int n0 = blockIdx.y * 64, j0 = blockIdx.x * 64;
    int c = tid & 63, r0 = tid >> 6;
    for (int i = 0; i < 16; i++) {
        int r = r0 + i * 4;
        tl[r][c] = Xrow[((size_t)b * NN + n0 + r) * 384 + j0 + c];
    }
    __syncthreads();
    int c2 = tid & 31, r4 = tid >> 5;
    unsigned short* ob = Xt + ((size_t)b * 384 + j0) * NN + n0;
    for (int i = 0; i < 8; i++) {
        int jr = r4 + i * 8;
        unsigned int v0 = (unsigned int)tl[2 * c2][jr] | ((unsigned int)tl[2 * c2 + 1][jr] << 16);
        *(unsigned int*)(ob + (size_t)jr * NN + 2 * c2) = v0;
    }
}

// ---------------- tiled P ----------------
__global__ __launch_bounds__(256) void k_Ptile(const float* __restrict__ l2,
                                               const float* __restrict__ r2,
                                               const float* __restrict__ bsin,
                                               unsigned short* __restrict__ Pt)
{
    __shared__ float l2s[64][13];
    __shared__ float r2s[12][64];
    __shared__ float bsS[64][65];
    int k0 = blockIdx.x * 64, m0 = blockIdx.y * 64, b = blockIdx.z;
    int tid = threadIdx.x;
    for (int i = tid; i < 768; i += 256) {
        int r = i / 12, t = i - r * 12;
        l2s[r][t] = l2[((size_t)b * NN + m0 + r) * 12 + t];
    }
    for (int i = tid; i < 768; i += 256) {
        int t = i >> 6, k = i & 63;
        r2s[t][k] = r2[((size_t)b * 12 + t) * NN + k0 + k];
    }
    for (int i = tid; i < 4096; i += 256) {
        int r = i >> 6, c = i & 63;
        bsS[r][c] = bsin[(size_t)(m0 + r) * NN + k0 + c];
    }
    __syncthreads();
    int m = tid & 63, kg = tid >> 6;
    float lv[12];
#pragma unroll
    for (int t = 0; t < 12; t++) lv[t] = l2s[m][t];
#pragma unroll
    for (int s = 0; s < 16; s++) {
        int kl = kg * 16 + s;
        float p = bsS[m][kl];
#pragma unroll
        for (int t = 0; t < 12; t++) p += lv[t] * r2s[t][kl];
        float sg = 1.f / (1.f + expf(-p));
        Pt[((size_t)b * NN + k0 + kl) * NN + m0 + m] = cvt_bf(sg);
    }
}

// bf16 transpose 1024x1024
__global__ __launch_bounds__(256) void k_tb16(const unsigned short* __restrict__ s,
                                              unsigned short* __restrict__ d)
{
    __shared__ unsigned short tl[64][65];
    int r0 = blockIdx.y * 64, c0 = blockIdx.x * 64;
    int tid = threadIdx.x;
    int c = tid & 63, rr = tid >> 6;
    for (int i = 0; i < 16; i++)
        tl[rr + i * 4][c] = s[(size_t)(r0 + rr + i * 4) * NN + c0 + c];
    __syncthreads();
    for (int i = 0; i < 16; i++)
        d[(size_t)(c0 + rr + i * 4) * NN + r0 + c] = tl[c][rr + i * 4];
}

// ---------------- 8-phase 256x256 S-GEMM: expB[b] = bf16(exp(Vs @ Pt[b]^T)) + colsum ----------------
__device__ inline void stage2(const short* __restrict__ g, int grow0, int gk0,
                              short* dstbase, int tid)
{
#pragma unroll
    for (int o = 0; o < 2; o++) {
        int y = o * 8192 + tid * 16;
        int rowh = y >> 7;
        int colb = (y & 127) ^ ((rowh & 7) << 4);
        const short* src = g + (size_t)(grow0 + rowh) * NN + gk0 + (colb >> 1);
        gll16(src, dstbase + (y >> 1));
    }
}

__global__ __launch_bounds__(512, 2) void sgemm8(const short* __restrict__ A,
                                                 const short* __restrict__ Bm,
                                                 unsigned short* __restrict__ expB,
                                                 float* __restrict__ colsum)
{
    int bz = blockIdx.z;
    const short* Bb = Bm + (size_t)bz * NN * NN;
    int i0 = blockIdx.y * 256, j0 = blockIdx.x * 256;
    __shared__ short sm[65536];
    int tid = threadIdx.x;
    int ln = tid & 63, wv = tid >> 6;
    int wm = (wv >> 2) * 128, wn = (wv & 3) * 64;
    int fr = ln & 15, fk = ln >> 4;
    int ahalf = wv >> 2;
    int bhalf = wn >> 7;
    int bcol = wn & 64;
    int swz = (fr & 7) << 4;
    int kcol0 = ((fk * 16) ^ swz) >> 1;
    int kcol1 = ((64 + fk * 16) ^ swz) >> 1;

    f32x4 acc[8][4];
#pragma unroll
    for (int m = 0; m < 8; m++)
#pragma unroll
        for (int n = 0; n < 4; n++) acc[m][n] = (f32x4)(0.f);

    stage2(Bb, j0 + 0,   0,  sm + 16384,        tid);
    stage2(Bb, j0 + 128, 0,  sm + 16384 + 8192, tid);
    stage2(A,  i0 + 0,   0,  sm + 0,            tid);
    stage2(A,  i0 + 128, 0,  sm + 8192,         tid);
    stage2(Bb, j0 + 0,   64, sm + 32768 + 16384,        tid);
    stage2(Bb, j0 + 128, 64, sm + 32768 + 16384 + 8192, tid);
    asm volatile("s_waitcnt vmcnt(4)" ::: "memory");
    __builtin_amdgcn_s_barrier();

    for (int i = 0; i < 8; i++) {
        bf16x8 bv[8];
#pragma unroll
        for (int ph = 0; ph < 8; ph++) {
            int t = 2 * i + (ph >> 2);
            int p = t & 1;
            int q = ph & 3;
            int abase = p * 32768 + ahalf * 8192;
            int bbase = p * 32768 + 16384 + bhalf * 8192;
            if (q == 0) {
#pragma unroll
                for (int nj = 0; nj < 4; nj++) {
                    int browh = bcol + nj * 16 + fr;
                    bv[nj * 2 + 0] = *(const bf16x8*)(sm + bbase + browh * 64 + kcol0);
                    bv[nj * 2 + 1] = *(const bf16x8*)(sm + bbase + browh * 64 + kcol1);
                }
            }
            bf16x8 av[4];
#pragma unroll
            for (int m2 = 0; m2 < 2; m2++) {
                int rowh = (2 * q + m2) * 16 + fr;
                av[m2 * 2 + 0] = *(const bf16x8*)(sm + abase + rowh * 64 + kcol0);
                av[m2 * 2 + 1] = *(const bf16x8*)(sm + abase + rowh * 64 + kcol1);
            }
            {
                int st, smat, shalf;
                if (ph == 0)      { st = 2 * i + 1; smat = 0; shalf = 0; }
                else if (ph == 1) { st = 2 * i + 1; smat = 0; shalf = 1; }
                else if (ph == 2) { st = 2 * i + 2; smat = 1; shalf = 0; }
                else if (ph == 3) { st = 2 * i + 2; smat = 1; shalf = 1; }
                else if (ph == 4) { st = 2 * i + 2; smat = 0; shalf = 0; }
                else if (ph == 5) { st = 2 * i + 2; smat = 0; shalf = 1; }
                else if (ph == 6) { st = 2 * i + 3; smat = 1; shalf = 0; }
                else              { st = 2 * i + 3; smat = 1; shalf = 1; }
                if (st < 16) {
                    short* dst = sm + (st & 1) * 32768 + smat * 16384 + shalf * 8192;
                    const short* g = smat ? Bb : A;
                    int grow0 = (smat ? j0 : i0) + shalf * 128;
                    stage2(g, grow0, st * 64, dst, tid);
                }
            }
            __builtin_amdgcn_s_barrier();
            __builtin_amdgcn_s_setprio(1);
#pragma unroll
            for (int m2 = 0; m2 < 2; m2++)
#pragma unroll
                for (int nj = 0; nj < 4; nj++) {
                    acc[2 * q + m2][nj] = __builtin_amdgcn_mfma_f32_16x16x32_bf16(
                        av[m2 * 2 + 0], bv[nj * 2 + 0], acc[2 * q + m2][nj], 0, 0, 0);
                    acc[2 * q + m2][nj] = __builtin_amdgcn_mfma_f32_16x16x32_bf16(
                        av[m2 * 2 + 1], bv[nj * 2 + 1], acc[2 * q + m2][nj], 0, 0, 0);
                }
            __builtin_amdgcn_s_setprio(0);
            if (ph == 3 || ph == 7) {
                if (i < 7) asm volatile("s_waitcnt vmcnt(4)" ::: "memory");
                else       asm volatile("s_waitcnt vmcnt(0)" ::: "memory");
            }
            __builtin_amdgcn_s_barrier();
        }
    }
    unsigned short* Cb = expB + (size_t)bz * NN * NN;
#pragma unroll
    for (int nj = 0; nj < 4; nj++) {
        int col = j0 + wn + nj * 16 + fr;
        float cs = 0.f;
#pragma unroll
        for (int m = 0; m < 8; m++) {
            int row = i0 + wm + m * 16 + fk * 4;
#pragma unroll
            for (int r = 0; r < 4; r++) {
                float e = expf(acc[m][nj][r]);
                Cb[(size_t)(row + r) * NN + col] = cvt_bf(e);
                cs += e;
            }
        }
        cs += __shfl_xor(cs, 16);
        cs += __shfl_xor(cs, 32);
        if (ln < 16) atomicAdd(&colsum[(size_t)bz * NN + col], cs);
    }
}

// ---------------- MFMA bf16 NT GEMM (MODE 3: split-K fp32 atomicAdd) ----------------
template<int MODE>
__global__ __launch_bounds__(256) void mgemm(const short* __restrict__ A,
                                             const short* __restrict__ B,
                                             void* __restrict__ Cv,
                                             int Kd, int kchunk,
                                             int ldA, int ldB, int ldC,
                                             long sA, long sB, long sC,
                                             float* __restrict__ colsum)
{
    int bz = blockIdx.z;
    const short* Ab = A + (size_t)bz * sA;
    const short* Bb = B + (size_t)bz * sB;
    int i0 = blockIdx.y * 128, j0 = blockIdx.x * 128;
    __shared__ short sm[16384];
    int tid = threadIdx.x;
    int ln = tid & 63, wv = tid >> 6;
    int wm = (wv >> 1) * 64, wn = (wv & 1) * 64;
    int fr = ln & 15, fk = ln >> 4;
    f32x4 acc[4][4];
#pragma unroll
    for (int a = 0; a < 4; a++)
#pragma unroll
        for (int b2 = 0; b2 < 4; b2++) acc[a][b2] = (f32x4)(0.f);

    int k_lo = 0, k_hi = Kd;
    if constexpr (MODE == 3) { k_lo = bz * kchunk; k_hi = k_lo + kchunk; }

    for (int k0 = k_lo; k0 < k_hi; k0 += 64) {
#pragma unroll
        for (int q = 0; q < 4; q++) {
            int e = q * 2048 + tid * 8;
            const short* src = Ab + (size_t)(i0 + (e >> 6)) * ldA + k0 + (e & 63);
            gll16(src, sm + e);
        }
#pragma unroll
        for (int q = 0; q < 4; q++) {
            int e = q * 2048 + tid * 8;
            const short* src = Bb + (size_t)(j0 + (e >> 6)) * ldB + k0 + (e & 63);
            gll16(src, sm + 8192 + e);
        }
        __syncthreads();
#pragma unroll
        for (int ks = 0; ks < 2; ks++) {
            bf16x8 av[4], bv[4];
#pragma unroll
            for (int mi = 0; mi < 4; mi++)
                av[mi] = *(const bf16x8*)(sm + (wm + mi * 16 + fr) * 64 + ks * 32 + fk * 8);
#pragma unroll
            for (int nj = 0; nj < 4; nj++)
                bv[nj] = *(const bf16x8*)(sm + 8192 + (wn + nj * 16 + fr) * 64 + ks * 32 + fk * 8);
#pragma unroll
            for (int mi = 0; mi < 4; mi++)
#pragma unroll
                for (int nj = 0; nj < 4; nj++)
                    acc[mi][nj] = __builtin_amdgcn_mfma_f32_16x16x32_bf16(av[mi], bv[nj], acc[mi][nj], 0, 0, 0);
        }
        __syncthreads();
    }
    if constexpr (MODE == 3) {
        float* Cb = (float*)Cv;
#pragma unroll
        for (int mi = 0; mi < 4; mi++)
#pragma unroll
            for (int nj = 0; nj < 4; nj++) {
                int row = i0 + wm + mi * 16 + fk * 4;
                int col = j0 + wn + nj * 16 + fr;
#pragma unroll
                for (int r = 0; r < 4; r++)
                    atomicAdd(&Cb[(size_t)(row + r) * ldC + col], acc[mi][nj][r]);
            }
    }
}

// ---------------- merged h-GEMMs: 768 blocks ----------------
__global__ __launch_bounds__(256) void mgemm_hh(const short* __restrict__ A1,
                                                const short* __restrict__ A2,
                                                const short* __restrict__ B,
                                                unsigned short* __restrict__ C1,
                                                unsigned short* __restrict__ C2)
{
    int id = blockIdx.x;
    int half = id / 384;
    int sid = id - half * 384;
    int xcd = sid & 7, jj = sid >> 3;
    int b = (xcd << 1) | (jj / 24);
    int r = jj % 24;
    int i0 = (r / 3) * 128, j0 = (r % 3) * 128;
    const short* Ab = (half ? A2 : A1) + (size_t)b * NN * NN;
    const short* Bb = B + (size_t)b * 384 * NN;
    unsigned short* C = half ? C2 : C1;
    __shared__ short sm[16384];
    int tid = threadIdx.x;
    int ln = tid & 63, wv = tid >> 6;
    int wm = (wv >> 1) * 64, wn = (wv & 1) * 64;
    int fr = ln & 15, fk = ln >> 4;
    f32x4 acc[4][4];
#pragma unroll
    for (int a = 0; a < 4; a++)
#pragma unroll
        for (int b2 = 0; b2 < 4; b2++) acc[a][b2] = (f32x4)(0.f);

    for (int k0 = 0; k0 < NN; k0 += 64) {
#pragma unroll
        for (int q = 0; q < 4; q++) {
            int e = q * 2048 + tid * 8;
            gll16(Ab + (size_t)(i0 + (e >> 6)) * NN + k0 + (e & 63), sm + e);
        }
#pragma unroll
        for (int q = 0; q < 4; q++) {
            int e = q * 2048 + tid * 8;
            gll16(Bb + (size_t)(j0 + (e >> 6)) * NN + k0 + (e & 63), sm + 8192 + e);
        }
        __syncthreads();
#pragma unroll
        for (int ks = 0; ks < 2; ks++) {
            bf16x8 av[4], bv[4];
#pragma unroll
            for (int mi = 0; mi < 4; mi++)
                av[mi] = *(const bf16x8*)(sm + (wm + mi * 16 + fr) * 64 + ks * 32 + fk * 8);
#pragma unroll
            for (int nj = 0; nj < 4; nj++)
                bv[nj] = *(const bf16x8*)(sm + 8192 + (wn + nj * 16 + fr) * 64 + ks * 32 + fk * 8);
#pragma unroll
            for (int mi = 0; mi < 4; mi++)
#pragma unroll
                for (int nj = 0; nj < 4; nj++)
                    acc[mi][nj] = __builtin_amdgcn_mfma_f32_16x16x32_bf16(av[mi], bv[nj], acc[mi][nj], 0, 0, 0);
        }
        __syncthreads();
    }
#pragma unroll
    for (int mi = 0; mi < 4; mi++)
#pragma unroll
        for (int nj = 0; nj < 4; nj++) {
            int row = i0 + wm + mi * 16 + fk * 4;
            int col = j0 + wn + nj * 16 + fr;
#pragma unroll
            for (int r2 = 0; r2 < 4; r2++)
                C[((size_t)b * NN + row + r2) * 384 + col] = cvt_bf(acc[mi][nj][r2]);
        }
}

// ---------------- normalize + threshold + At1 + At2 + sdiag (bf16 expB; round-11 grid) ----------------
__global__ __launch_bounds__(256) void k_normprep2(const unsigned short* __restrict__ expB,
                                                   float* __restrict__ spat,
                                                   const float* __restrict__ colsum,
                                                   const float* __restrict__ sup,
                                                   const float* __restrict__ supsq,
                                                   unsigned short* __restrict__ At1,
                                                   unsigned short* __restrict__ At2,
                                                   float* __restrict__ sdiag)
{
    __shared__ unsigned short t1[64][66];
    __shared__ unsigned short t2[64][66];
    int b = blockIdx.z;
    int n0 = blockIdx.y * 64, m0 = blockIdx.x * 64;
    int tid = threadIdx.x;
    int c = tid & 63, r0 = tid >> 6;
    const float thr = (1.0f / 1024.0f) / 0.6f;
    float inv = 1.f / colsum[(size_t)b * NN + m0 + c];
    const unsigned short* eb = expB + (size_t)b * NN * NN;
    float* sp = spat + (size_t)b * NN * NN;
    for (int i = 0; i < 16; i++) {
        int r = r0 + i * 4;
        size_t idx = (size_t)(n0 + r) * NN + m0 + c;
        float v = bf2f(eb[idx]) * inv;
        v = (v < thr) ? 0.f : v;
        sp[idx] = v;
        if (n0 + r == m0 + c) sdiag[(size_t)b * NN + n0 + r] = v;
        t1[r][c] = cvt_bf(sup[(size_t)(n0 + r) * NN + m0 + c] * v);
        float p2 = 2.f * supsq[(size_t)(n0 + r) * NN + m0 + c]
                 - (((n0 + r) == (m0 + c)) ? 1.f : 0.f);
        t2[r][c] = cvt_bf(p2 * v);
    }
    __syncthreads();
    int c2 = tid & 31, r4 = tid >> 5;
    size_t ob = ((size_t)b * NN + m0) * NN + n0;
    for (int i = 0; i < 8; i++) {
        int rr = r4 + i * 8;
        unsigned int v1 = (unsigned int)t1[2 * c2][rr] | ((unsigned int)t1[2 * c2 + 1][rr] << 16);
        unsigned int v2 = (unsigned int)t2[2 * c2][rr] | ((unsigned int)t2[2 * c2 + 1][rr] << 16);
        *(unsigned int*)(At1 + ob + (size_t)rr * NN + 2 * c2) = v1;
        *(unsigned int*)(At2 + ob + (size_t)rr * NN + 2 * c2) = v2;
    }
}

// ---------------- support graph ----------------
__global__ __launch_bounds__(256) void k_sup(const float* __restrict__ emb,
                                             float* __restrict__ sup,
                                             unsigned short* __restrict__ supB)
{
    int n = blockIdx.x, tid = threadIdx.x;
    __shared__ float en[16];
    if (tid < 16) en[tid] = emb[n * 16 + tid];
    __syncthreads();
    float v[4];
#pragma unroll
    for (int q = 0; q < 4; q++) {
        int m = q * 256 + tid;
        float d = 0.f;
#pragma unroll
        for (int dd = 0; dd < 16; dd++) d += en[dd] * emb[m * 16 + dd];
        v[q] = fmaxf(d, 0.f);
    }
    float mx = fmaxf(fmaxf(v[0], v[1]), fmaxf(v[2], v[3]));
    for (int o = 32; o > 0; o >>= 1) mx = fmaxf(mx, __shfl_xor(mx, o));
    __shared__ float red[4];
    if ((tid & 63) == 0) red[tid >> 6] = mx;
    __syncthreads();
    mx = fmaxf(fmaxf(red[0], red[1]), fmaxf(red[2], red[3]));
    float e[4];
    float s = 0.f;
#pragma unroll
    for (int q = 0; q < 4; q++) { e[q] = expf(v[q] - mx); s += e[q]; }
    for (int o = 32; o > 0; o >>= 1) s += __shfl_xor(s, o);
    __shared__ float red2[4];
    if ((tid & 63) == 0) red2[tid >> 6] = s;
    __syncthreads();
    s = red2[0] + red2[1] + red2[2] + red2[3];
    float inv = 1.f / s;
#pragma unroll
    for (int q = 0; q < 4; q++) {
        float val = e[q] * inv;
        sup[(size_t)n * NN + q * 256 + tid] = val;
        supB[(size_t)n * NN + q * 256 + tid] = cvt_bf(val);
    }
}

// ---------------- merged weight prep ----------------
__global__ __launch_bounds__(256) void k_wprep(const float* __restrict__ tcv,
                                               const float* __restrict__ tcg,
                                               const float* __restrict__ Theta,
                                               const float* __restrict__ rcw,
                                               unsigned short* __restrict__ Wr,
                                               unsigned short* __restrict__ Th,
                                               unsigned short* __restrict__ Rc)
{
    int tid = threadIdx.x;
    if (blockIdx.x < 64) {
        int o = blockIdx.x;
        float t = 0.f, p = 0.f;
        if (tid < 192) { t = tcv[o * 192 + tid]; p = t * t; }
        for (int off = 32; off > 0; off >>= 1) p += __shfl_xor(p, off);
        __shared__ float wsr[3];
        if (tid < 192 && (tid & 63) == 0) wsr[tid >> 6] = p;
        __syncthreads();
        if (tid < 192) {
            float sum = wsr[0] + wsr[1] + wsr[2];
            int c = tid / 3, dt = tid - c * 3;
            Wr[o * 192 + dt * 64 + c] = cvt_bf(t * (tcg[o] / sqrtf(sum)));
        }
    } else {
        for (int i = tid; i < 6144; i += 256) {
            int o = i / 96, rem = i - o * 96;
            int kind = rem >> 5, f = rem & 31;
            Th[i] = cvt_bf(Theta[kind * 2048 + f * 64 + o]);
        }
        for (int i = tid; i < 2048; i += 256) Rc[i] = cvt_bf(rcw[i]);
    }
}

// ---------------- MFMA fused tail (reads Xrow bf16) ----------------
__global__ __launch_bounds__(256) void k_tail(const unsigned short* __restrict__ Xrow,
                                              const unsigned short* __restrict__ h1,
                                              const unsigned short* __restrict__ h2,
                                              const float* __restrict__ sdiag,
                                              const unsigned short* __restrict__ Th,
                                              const unsigned short* __restrict__ Wr,
                                              const unsigned short* __restrict__ Rc,
                                              const float* __restrict__ tcb,
                                              const float* __restrict__ rcb,
                                              const float* __restrict__ lnw,
                                              const float* __restrict__ lnb,
                                              float* __restrict__ out)
{
    int b = blockIdx.y;
    int node0 = blockIdx.x * 4;
    int tid = threadIdx.x;
    int ln = tid & 63, wv = tid >> 6;
    int fr = ln & 15, fk = ln >> 4;

    __shared__ union {
        struct { unsigned short xt[1920], h1t[1920], h2t[1920], gcn[4032]; } a;
        float Y[48 * 65];
    } u;
    __shared__ float sdp[48];
    __shared__ float lnwS[64], lnbS[64], tbS[64];
    __shared__ float muS[48], rsS[48];

    size_t rowb = ((size_t)b * NN + node0) * 384;
    {
        const unsigned int* xp = (const unsigned int*)(Xrow + rowb);
        const unsigned int* h1p = (const unsigned int*)(h1 + rowb);
        const unsigned int* h2p = (const unsigned int*)(h2 + rowb);
        for (int q = tid; q < 768; q += 256) {
            int j0 = q * 2;
            int node = j0 / 384, j = j0 - node * 384;
            int f = j / 12, t = j - f * 12;
            int t2 = t + 1, f2 = f;
            if (t2 == 12) { t2 = 0; f2 = f + 1; }
            int la0 = node * 480 + t * 40 + f;
            int la1 = node * 480 + t2 * 40 + f2;
            unsigned int wx = xp[q], w1 = h1p[q], w2 = h2p[q];
            u.a.xt[la0] = (unsigned short)(wx & 0xffff); u.a.xt[la1] = (unsigned short)(wx >> 16);
            u.a.h1t[la0] = (unsigned short)(w1 & 0xffff); u.a.h1t[la1] = (unsigned short)(w1 >> 16);
            u.a.h2t[la0] = (unsigned short)(w2 & 0xffff); u.a.h2t[la1] = (unsigned short)(w2 >> 16);
        }
    }
    for (int i = tid; i < 576; i += 256) {
        int node = i / 144, r = i - node * 144;
        int rr = (r < 72) ? 0 : 13;
        u.a.gcn[node * 1008 + rr * 72 + (r % 72)] = 0;
    }
    if (tid < 48) sdp[tid] = sdiag[(size_t)b * NN + node0 + tid / 12];
    if (tid < 64) { lnwS[tid] = lnw[tid]; lnbS[tid] = lnb[tid]; tbS[tid] = tcb[tid] + rcb[tid]; }

    int ocol = wv * 16 + fr;
    bf16x8 bTh[3], bWr[6], bRc;
#pragma unroll
    for (int kb = 0; kb < 3; kb++)
        bTh[kb] = *(const bf16x8*)((const short*)Th + (size_t)ocol * 96 + kb * 32 + fk * 8);
#pragma unroll
    for (int kb = 0; kb < 6; kb++)
        bWr[kb] = *(const bf16x8*)((const short*)Wr + (size_t)ocol * 192 + kb * 32 + fk * 8);
    bRc = *(const bf16x8*)((const short*)Rc + (size_t)ocol * 32 + fk * 8);

    int na[3], ta[3];
#pragma unroll
    for (int rb = 0; rb < 3; rb++) {
        int p = rb * 16 + fr;
        na[rb] = p / 12; ta[rb] = p - na[rb] * 12;
    }
    __syncthreads();

    f32x4 acc[3];
#pragma unroll
    for (int rb = 0; rb < 3; rb++) {
        int ax = na[rb] * 480 + ta[rb] * 40 + fk * 8;
        bf16x8 avx = *(const bf16x8*)(u.a.xt + ax);
        f32x4 z = (f32x4)(0.f);
        acc[rb] = __builtin_amdgcn_mfma_f32_16x16x32_bf16(avx, bTh[0], z, 0, 0, 0);
#pragma unroll
        for (int r = 0; r < 4; r++) acc[rb][r] *= sdp[rb * 16 + fk * 4 + r];
        bf16x8 av1 = *(const bf16x8*)(u.a.h1t + ax);
        acc[rb] = __builtin_amdgcn_mfma_f32_16x16x32_bf16(av1, bTh[1], acc[rb], 0, 0, 0);
        bf16x8 av2 = *(const bf16x8*)(u.a.h2t + ax);
        acc[rb] = __builtin_amdgcn_mfma_f32_16x16x32_bf16(av2, bTh[2], acc[rb], 0, 0, 0);
    }
#pragma unroll
    for (int rb = 0; rb < 3; rb++) {
#pragma unroll
        for (int r = 0; r < 4; r++) {
            int pc = rb * 16 + fk * 4 + r;
            int nc = pc / 12, tc2 = pc - nc * 12;
            u.a.gcn[nc * 1008 + (tc2 + 1) * 72 + wv * 16 + fr] = cvt_bf(fmaxf(acc[rb][r], 0.f));
        }
    }
    __syncthreads();
#pragma unroll
    for (int rb = 0; rb < 3; rb++) {
        f32x4 a2 = (f32x4)(0.f);
#pragma unroll
        for (int kb = 0; kb < 6; kb++) {
            int dt = kb >> 1, c0 = (kb & 1) * 32;
            bf16x8 ag = *(const bf16x8*)(u.a.gcn + na[rb] * 1008 + (ta[rb] + dt) * 72 + c0 + fk * 8);
            a2 = __builtin_amdgcn_mfma_f32_16x16x32_bf16(ag, bWr[kb], a2, 0, 0, 0);
        }
        int ax = na[rb] * 480 + ta[rb] * 40 + fk * 8;
        bf16x8 avx = *(const bf16x8*)(u.a.xt + ax);
        acc[rb] = __builtin_amdgcn_mfma_f32_16x16x32_bf16(avx, bRc, a2, 0, 0, 0);
    }
    __syncthreads();
    float tb = tbS[ocol];
#pragma unroll
    for (int rb = 0; rb < 3; rb++)
#pragma unroll
        for (int r = 0; r < 4; r++)
            u.Y[(rb * 16 + fk * 4 + r) * 65 + ocol] = acc[rb][r] + tb;
    __syncthreads();
    if (tid < 48) {
        float s = 0.f, s2 = 0.f;
        for (int o = 0; o < 64; o++) {
            float v = u.Y[tid * 65 + o];
            s += v; s2 += v * v;
        }
        float mm = s * (1.f / 64.f);
        float var = s2 * (1.f / 64.f) - mm * mm;
        muS[tid] = mm; rsS[tid] = rsqrtf(var + 1e-5f);
    }
    __syncthreads();
    float2* obv = (float2*)(out + rowb * 2);
    for (int q = tid; q < 1536; q += 256) {
        int i = q * 2;
        int node = i / 768, rr = i - node * 768;
        int o = rr / 12, t = rr - o * 12;
        int p0 = node * 12 + t;
        float v0 = (u.Y[p0 * 65 + o] - muS[p0]) * rsS[p0] * lnwS[o] + lnbS[o];
        int t1 = t + 1, o1 = o;
        if (t1 == 12) { t1 = 0; o1 = o + 1; }
        int p1 = node * 12 + t1;
        float v1 = (u.Y[p1 * 65 + o1] - muS[p1]) * rsS[p1] * lnwS[o1] + lnbS[o1];
        float2 pk; pk.x = v0; pk.y = v1;
        obv[q] = pk;
    }
}

extern "C" void kernel_launch(void* const* d_in, const int* in_sizes, int n_in,
                              void* d_out, int out_size, void* d_ws, size_t ws_size,
                              hipStream_t stream)
{
    const float* x    = (const float*)d_in[0];
    const float* emb  = (const float*)d_in[1];
    const float* W1   = (const float*)d_in[2];
    const float* W2   = (const float*)d_in[3];
    const float* W3   = (const float*)d_in[4];
    const float* bs   = (const float*)d_in[5];
    const float* Vs   = (const float*)d_in[6];
    const float* U1   = (const float*)d_in[7];
    const float* U2   = (const float*)d_in[8];
    const float* U3   = (const float*)d_in[9];
    const float* be   = (const float*)d_in[10];
    const float* Ve   = (const float*)d_in[11];
    const float* Theta= (const float*)d_in[12];
    const float* tcv  = (const float*)d_in[13];
    const float* tcg  = (const float*)d_in[14];
    const float* tcb  = (const float*)d_in[15];
    const float* rcw  = (const float*)d_in[16];
    const float* rcb  = (const float*)d_in[17];
    const float* lnw  = (const float*)d_in[18];
    const float* lnb  = (const float*)d_in[19];

    float* xres = (float*)d_out;                       // B*N*FT*T fp32 (scratch for At2 until k_tail)
    float* spat = xres + (size_t)NB * NN * NFT * NT;   // B*N*N fp32

    char* base = (char*)d_ws;                          // compact layout (~140 MB total, L3-resident)
    unsigned short* Xrow = (unsigned short*)(base + 0);            // 12.6 MB, live -> k_tail
    unsigned short* Pt   = (unsigned short*)(base + 16777216);     // 33.5 MB (dead after sgemm8)
    unsigned short* At1  = (unsigned short*)(base + 16777216);     // reuses Pt region
    unsigned short* expB = (unsigned short*)(base + 50331648);     // 33.5 MB
    unsigned short* At2  = (unsigned short*)xres;                  // d_out scratch
    unsigned short* Xt   = (unsigned short*)(base + 83886080);     // 12.6 MB
    unsigned short* h1   = (unsigned short*)(base + 96468992);     // 12.6 MB
    unsigned short* h2   = (unsigned short*)(base + 109051904);    // 12.6 MB
    unsigned short* Vsb  = (unsigned short*)(base + 121634816);    // 2 MB
    float* colsum  = (float*)(base + 123731968);
    float* sdiag   = (float*)(base + 123797504);
    float* sup     = (float*)(base + 123863040);
    unsigned short* supB = (unsigned short*)(base + 128057344);
    unsigned short* supT = (unsigned short*)(base + 130154496);
    float* supsq   = (float*)(base + 132251648);
    float* lhs_pre = (float*)(base + 136445952);
    float* M2      = (float*)(base + 136470528);
    float* rhs     = (float*)(base + 136495104);
    float* rr3     = (float*)(base + 137281536);
    float* E       = (float*)(base + 138067968);
    float* EW1     = (float*)(base + 138077184);
    float* l2      = (float*)(base + 138078208);
    float* r2      = (float*)(base + 138864640);
    unsigned short* Wr = (unsigned short*)(base + 139651072);
    unsigned short* Th = (unsigned short*)(base + 139675648);
    unsigned short* Rc = (unsigned short*)(base + 139687936);

    hipMemsetAsync(lhs_pre, 0, 49152, stream);             // lhs_pre + M2 (contiguous)
    hipMemsetAsync(supsq, 0, (size_t)NN * NN * sizeof(float), stream);

    // pre-pass: x fp32 -> lhs_pre, rhs, rr3, Xrow(bf16)
    k_pre<<<dim3(16, 16), 384, 0, stream>>>(x, U1, U3, W3, lhs_pre, rhs, rr3, Xrow);
    k_M2<<<dim3(16, 32), 384, 0, stream>>>(U2, rhs, M2);
    k_E<<<16, 192, 0, stream>>>(lhs_pre, M2, be, Ve, W1, E, EW1);
    // spatial attention
    k_l2r2x<<<dim3(128, 16), 384, 0, stream>>>(Xrow, rr3, E, EW1, W2, l2, r2);
    k_xt<<<dim3(6, 16, 16), 256, 0, stream>>>(Xrow, Xt, Vs, Vsb);
    k_Ptile<<<dim3(16, 16, 16), 256, 0, stream>>>(l2, r2, bs, Pt);
    hipMemsetAsync(colsum, 0, (size_t)NB * NN * sizeof(float), stream);
    // 8-phase 256^2 S-GEMM: exp stored bf16 + colsum
    sgemm8<<<dim3(4, 4, 16), 512, 0, stream>>>((const short*)Vsb, (const short*)Pt,
                                               expB, colsum);
    // graph supports
    k_sup<<<1024, 256, 0, stream>>>(emb, sup, supB);
    k_tb16<<<dim3(16, 16), 256, 0, stream>>>(supB, supT);
    mgemm<3><<<dim3(8, 8, 4), 256, 0, stream>>>((const short*)supB, (const short*)supT,
        (void*)supsq, NN, 256, NN, NN, NN, 0L, 0L, 0L, nullptr);
    // normalize + threshold + masked adjacencies + diagonal
    k_normprep2<<<dim3(16, 16, 16), 256, 0, stream>>>(expB, spat, colsum, sup, supsq,
                                                      At1, At2, sdiag);
    // merged h-GEMMs
    mgemm_hh<<<768, 256, 0, stream>>>((const short*)At1, (const short*)At2,
                                      (const short*)Xt, h1, h2);
    // tail
    k_wprep<<<65, 256, 0, stream>>>(tcv, tcg, Theta, rcw, Wr, Th, Rc);
    k_tail<<<dim3(256, 16), 256, 0, stream>>>(Xrow, h1, h2, sdiag, Th, Wr, Rc,
                                              tcb, rcb, lnw, lnb, xres);
}

// Round 14
// 287.466 us; speedup vs baseline: 1.0579x; 1.0354x over previous
//
#include <hip/hip_runtime.h>
#include <math.h>

#define NB 16      // B
#define NN 1024    // N
#define NF 32      // F
#define NT 12      // T
#define NFC 64
#define NFT 64

typedef __attribute__((ext_vector_type(8))) short bf16x8;
typedef __attribute__((ext_vector_type(4))) float f32x4;

__device__ inline unsigned short cvt_bf(float f) {
    unsigned int u = __float_as_uint(f);
    u += 0x7fff + ((u >> 16) & 1);
    return (unsigned short)(u >> 16);
}
__device__ inline float bf2f(unsigned short u) {
    return __uint_as_float(((unsigned int)u) << 16);
}
__device__ inline void gll16(const short* g, short* l) {
    __builtin_amdgcn_global_load_lds((const __attribute__((address_space(1))) void*)g,
                                     (__attribute__((address_space(3))) void*)l, 16, 0, 0);
}

// ---------------- fused pre-pass: lhs_pre (U1), rhs (U3), rr3 (W3), Xrow (bf16) ----------------
__global__ __launch_bounds__(384) void k_pre(const float* __restrict__ x,
                                             const float* __restrict__ U1,
                                             const float* __restrict__ U3,
                                             const float* __restrict__ W3,
                                             float* __restrict__ lhs_pre,
                                             float* __restrict__ rhs,
                                             float* __restrict__ rr3,
                                             unsigned short* __restrict__ Xrow)
{
    __shared__ float xs[8 * 384];
    int b = blockIdx.x, ch = blockIdx.y, tid = threadIdx.x;
    float acc = 0.f;
    for (int c8 = 0; c8 < 8; c8++) {
        int n0 = ch * 64 + c8 * 8;
        size_t r0 = (size_t)b * NN + n0;
        __syncthreads();
        for (int i = 0; i < 8; i++) xs[i * 384 + tid] = x[(r0 + i) * 384 + tid];
        __syncthreads();
        for (int i = 0; i < 8; i++) acc += xs[i * 384 + tid] * U1[n0 + i];
        for (int idx = tid; idx < 1536; idx += 384) {
            int row = idx / 192, jj = (idx - row * 192) * 2;
            unsigned int w = (unsigned int)cvt_bf(xs[row * 384 + jj])
                           | ((unsigned int)cvt_bf(xs[row * 384 + jj + 1]) << 16);
            *(unsigned int*)(Xrow + (r0 + row) * 384 + jj) = w;
        }
        if (tid < 192) {
            int half = tid / 96;
            int r = tid - half * 96;
            int i = r / 12, t = r - i * 12;
            const float* wv = half ? W3 : U3;
            float s = 0.f;
            for (int f = 0; f < 32; f++) s += wv[f] * xs[i * 384 + f * 12 + t];
            float* outp = half ? rr3 : rhs;
            outp[(r0 + i) * 12 + t] = s;
        }
    }
    int f = tid / 12, t = tid - f * 12;
    atomicAdd(&lhs_pre[b * 384 + t * 32 + f], acc);
}

// M2[b][f][u] = sum_n U2[f][n] * rhs[b][n][u]
__global__ __launch_bounds__(384) void k_M2(const float* __restrict__ U2,
                                            const float* __restrict__ rhs,
                                            float* __restrict__ M2)
{
    int b = blockIdx.x, ch = blockIdx.y, tid = threadIdx.x;
    int f = tid / 12, u = tid - (tid / 12) * 12;
    int n0 = ch * 32;
    float a = 0.f;
    for (int n = n0; n < n0 + 32; n++)
        a += U2[(size_t)f * NN + n] * rhs[((size_t)b * NN + n) * 12 + u];
    atomicAdd(&M2[b * 384 + f * 12 + u], a);
}

// E (softmax over t) + EW1; prod inline
__global__ __launch_bounds__(192) void k_E(const float* __restrict__ lhs_pre,
                                           const float* __restrict__ M2,
                                           const float* __restrict__ be,
                                           const float* __restrict__ Ve,
                                           const float* __restrict__ W1,
                                           float* __restrict__ E,
                                           float* __restrict__ EW1)
{
    int b = blockIdx.x, tid = threadIdx.x;
    __shared__ float lp2[384], m2s[384];
    __shared__ float ssig[144], sE[144], mx[12], sm[12];
    for (int i = tid; i < 384; i += 192) {
        lp2[i] = lhs_pre[b * 384 + i];
        m2s[i] = M2[b * 384 + i];
    }
    __syncthreads();
    if (tid < 144) {
        int s = tid / 12, u = tid - s * 12;
        float p = 0.f;
#pragma unroll
        for (int f = 0; f < 32; f++) p += lp2[s * 32 + f] * m2s[f * 12 + u];
        ssig[tid] = 1.f / (1.f + expf(-(p + be[tid])));
    }
    __syncthreads();
    if (tid < 144) {
        int t = tid / 12, u = tid - t * 12;
        float a = 0.f;
        for (int s2 = 0; s2 < 12; s2++) a += Ve[t * 12 + s2] * ssig[s2 * 12 + u];
        sE[tid] = a;
    }
    __syncthreads();
    if (tid < 12) {
        float m = -1e30f;
        for (int t = 0; t < 12; t++) m = fmaxf(m, sE[t * 12 + tid]);
        float s = 0.f;
        for (int t = 0; t < 12; t++) s += expf(sE[t * 12 + tid] - m);
        mx[tid] = m; sm[tid] = s;
    }
    __syncthreads();
    float val = 0.f;
    if (tid < 144) {
        int u = tid % 12;
        val = expf(sE[tid] - mx[u]) / sm[u];
        E[b * 144 + tid] = val;
    }
    __syncthreads();
    if (tid < 144) sE[tid] = val;
    __syncthreads();
    if (tid < 12) {
        float a = 0.f;
        for (int u = 0; u < 12; u++) a += sE[tid * 12 + u] * W1[u];
        EW1[b * 12 + tid] = a;
    }
}

// ---------------- l2/r2 from Xrow (bf16, packed loads) ----------------
__global__ __launch_bounds__(384) void k_l2r2x(const unsigned short* __restrict__ Xrow,
                                               const float* __restrict__ rr3,
                                               const float* __restrict__ E,
                                               const float* __restrict__ EW1,
                                               const float* __restrict__ W2,
                                               float* __restrict__ l2,
                                               float* __restrict__ r2)
{
    __shared__ float xs[8 * 384];
    __shared__ float Es[144], ew[12], rrs[96], lp[8][32];
    int b = blockIdx.y, tid = threadIdx.x;
    int n0 = blockIdx.x * 8;
    size_t r0 = (size_t)b * NN + n0;
    if (tid < 144) Es[tid] = E[b * 144 + tid];
    if (tid < 12) ew[tid] = EW1[b * 12 + tid];
    if (tid < 96) rrs[tid] = rr3[(r0 + tid / 12) * 12 + (tid % 12)];
    const unsigned int* Xr = (const unsigned int*)(Xrow + r0 * 384);
    for (int i2 = tid; i2 < 1536; i2 += 384) {
        unsigned int w = Xr[i2];
        xs[2 * i2]     = bf2f((unsigned short)(w & 0xffff));
        xs[2 * i2 + 1] = bf2f((unsigned short)(w >> 16));
    }
    __syncthreads();
    if (tid < 256) {
        int i = tid >> 5, f = tid & 31;
        float a = 0.f;
#pragma unroll
        for (int t = 0; t < 12; t++) a += xs[i * 384 + f * 12 + t] * ew[t];
        lp[i][f] = a;
    }
    __syncthreads();
    if (tid < 96) {
        int i = tid / 12, u = tid - i * 12;
        float a = 0.f;
        for (int f = 0; f < 32; f++) a += lp[i][f] * W2[f * 12 + u];
        l2[(r0 + i) * 12 + u] = a;
        float rv = 0.f;
#pragma unroll
        for (int t = 0; t < 12; t++) rv += rrs[i * 12 + t] * Es[t * 12 + u];
        r2[((size_t)b * 12 + u) * NN + n0 + i] = rv;
    }
}

// Xt[b][j][n] = Xrow[b][n][j]; flat blocks < 1024 also convert Vs row -> bf16
__global__ __launch_bounds__(256) void k_xt(const unsigned short* __restrict__ Xrow,
                                            unsigned short* __restrict__ Xt,
                                            const float* __restrict__ Vs,
                                            unsigned short* __restrict__ Vsb)
{
    int tid = threadIdx.x;
    int fid = blockIdx.x + 6 * (blockIdx.y + 16 * blockIdx.z);
    if (fid < 1024) {
        size_t i = (size_t)fid * 1024 + tid * 4;
        float4 v = *(const float4*)(Vs + i);
        unsigned int p0 = (unsigned int)cvt_bf(v.x) | ((unsigned int)cvt_bf(v.y) << 16);
        unsigned int p1 = (unsigned int)cvt_bf(v.z) | ((unsigned int)cvt_bf(v.w) << 16);
        *(unsigned int*)(Vsb + i) = p0;
        *(unsigned int*)(Vsb + i + 2) = p1;
    }
    __shared__ unsigned short tl[64][66];
    int b = blockIdx.z;
    int n0 = blockIdx.y * 64, j0 = blockIdx.x * 64;
    int c = tid & 63, r0 = tid >> 6;
    for (int i = 0; i < 16; i++) {
        int r = r0 + i * 4;
        tl[r][c] = Xrow[((size_t)b * NN + n0 + r) * 384 + j0 + c];
    }
    __syncthreads();
    int c2 = tid & 31, r4 = tid >> 5;
    unsigned short* ob = Xt + ((size_t)b * 384 + j0) * NN + n0;
    for (int i = 0; i < 8; i++) {
        int jr = r4 + i * 8;
        unsigned int v0 = (unsigned int)tl[2 * c2][jr] | ((unsigned int)tl[2 * c2 + 1][jr] << 16);
        *(unsigned int*)(ob + (size_t)jr * NN + 2 * c2) = v0;
    }
}

// ---------------- tiled P (m0==0 blocks also zero colsum slice) ----------------
__global__ __launch_bounds__(256) void k_Ptile(const float* __restrict__ l2,
                                               const float* __restrict__ r2,
                                               const float* __restrict__ bsin,
                                               unsigned short* __restrict__ Pt,
                                               float* __restrict__ colsum)
{
    __shared__ float l2s[64][13];
    __shared__ float r2s[12][64];
    __shared__ float bsS[64][65];
    int k0 = blockIdx.x * 64, m0 = blockIdx.y * 64, b = blockIdx.z;
    int tid = threadIdx.x;
    if (m0 == 0 && tid < 64) colsum[(size_t)b * NN + k0 + tid] = 0.f;
    for (int i = tid; i < 768; i += 256) {
        int r = i / 12, t = i - r * 12;
        l2s[r][t] = l2[((size_t)b * NN + m0 + r) * 12 + t];
    }
    for (int i = tid; i < 768; i += 256) {
        int t = i >> 6, k = i & 63;
        r2s[t][k] = r2[((size_t)b * 12 + t) * NN + k0 + k];
    }
    for (int i = tid; i < 4096; i += 256) {
        int r = i >> 6, c = i & 63;
        bsS[r][c] = bsin[(size_t)(m0 + r) * NN + k0 + c];
    }
    __syncthreads();
    int m = tid & 63, kg = tid >> 6;
    float lv[12];
#pragma unroll
    for (int t = 0; t < 12; t++) lv[t] = l2s[m][t];
#pragma unroll
    for (int s = 0; s < 16; s++) {
        int kl = kg * 16 + s;
        float p = bsS[m][kl];
#pragma unroll
        for (int t = 0; t < 12; t++) p += lv[t] * r2s[t][kl];
        float sg = 1.f / (1.f + expf(-p));
        Pt[((size_t)b * NN + k0 + kl) * NN + m0 + m] = cvt_bf(sg);
    }
}

// bf16 transpose 1024x1024
__global__ __launch_bounds__(256) void k_tb16(const unsigned short* __restrict__ s,
                                              unsigned short* __restrict__ d)
{
    __shared__ unsigned short tl[64][65];
    int r0 = blockIdx.y * 64, c0 = blockIdx.x * 64;
    int tid = threadIdx.x;
    int c = tid & 63, rr = tid >> 6;
    for (int i = 0; i < 16; i++)
        tl[rr + i * 4][c] = s[(size_t)(r0 + rr + i * 4) * NN + c0 + c];
    __syncthreads();
    for (int i = 0; i < 16; i++)
        d[(size_t)(c0 + rr + i * 4) * NN + r0 + c] = tl[c][rr + i * 4];
}

// ---------------- 8-phase 256x256 S-GEMM: spat[b] = exp(Vs @ Pt[b]^T) fp32 + colsum ----------------
__device__ inline void stage2(const short* __restrict__ g, int grow0, int gk0,
                              short* dstbase, int tid)
{
#pragma unroll
    for (int o = 0; o < 2; o++) {
        int y = o * 8192 + tid * 16;
        int rowh = y >> 7;
        int colb = (y & 127) ^ ((rowh & 7) << 4);
        const short* src = g + (size_t)(grow0 + rowh) * NN + gk0 + (colb >> 1);
        gll16(src, dstbase + (y >> 1));
    }
}

__global__ __launch_bounds__(512, 2) void sgemm8(const short* __restrict__ A,
                                                 const short* __restrict__ Bm,
                                                 float* __restrict__ C,
                                                 float* __restrict__ colsum)
{
    int bz = blockIdx.z;
    const short* Bb = Bm + (size_t)bz * NN * NN;
    int i0 = blockIdx.y * 256, j0 = blockIdx.x * 256;
    __shared__ short sm[65536];
    int tid = threadIdx.x;
    int ln = tid & 63, wv = tid >> 6;
    int wm = (wv >> 2) * 128, wn = (wv & 3) * 64;
    int fr = ln & 15, fk = ln >> 4;
    int ahalf = wv >> 2;
    int bhalf = wn >> 7;
    int bcol = wn & 64;
    int swz = (fr & 7) << 4;
    int kcol0 = ((fk * 16) ^ swz) >> 1;
    int kcol1 = ((64 + fk * 16) ^ swz) >> 1;

    f32x4 acc[8][4];
#pragma unroll
    for (int m = 0; m < 8; m++)
#pragma unroll
        for (int n = 0; n < 4; n++) acc[m][n] = (f32x4)(0.f);

    stage2(Bb, j0 + 0,   0,  sm + 16384,        tid);
    stage2(Bb, j0 + 128, 0,  sm + 16384 + 8192, tid);
    stage2(A,  i0 + 0,   0,  sm + 0,            tid);
    stage2(A,  i0 + 128, 0,  sm + 8192,         tid);
    stage2(Bb, j0 + 0,   64, sm + 32768 + 16384,        tid);
    stage2(Bb, j0 + 128, 64, sm + 32768 + 16384 + 8192, tid);
    asm volatile("s_waitcnt vmcnt(4)" ::: "memory");
    __builtin_amdgcn_s_barrier();

    for (int i = 0; i < 8; i++) {
        bf16x8 bv[8];
#pragma unroll
        for (int ph = 0; ph < 8; ph++) {
            int t = 2 * i + (ph >> 2);
            int p = t & 1;
            int q = ph & 3;
            int abase = p * 32768 + ahalf * 8192;
            int bbase = p * 32768 + 16384 + bhalf * 8192;
            if (q == 0) {
#pragma unroll
                for (int nj = 0; nj < 4; nj++) {
                    int browh = bcol + nj * 16 + fr;
                    bv[nj * 2 + 0] = *(const bf16x8*)(sm + bbase + browh * 64 + kcol0);
                    bv[nj * 2 + 1] = *(const bf16x8*)(sm + bbase + browh * 64 + kcol1);
                }
            }
            bf16x8 av[4];
#pragma unroll
            for (int m2 = 0; m2 < 2; m2++) {
                int rowh = (2 * q + m2) * 16 + fr;
                av[m2 * 2 + 0] = *(const bf16x8*)(sm + abase + rowh * 64 + kcol0);
                av[m2 * 2 + 1] = *(const bf16x8*)(sm + abase + rowh * 64 + kcol1);
            }
            {
                int st, smat, shalf;
                if (ph == 0)      { st = 2 * i + 1; smat = 0; shalf = 0; }
                else if (ph == 1) { st = 2 * i + 1; smat = 0; shalf = 1; }
                else if (ph == 2) { st = 2 * i + 2; smat = 1; shalf = 0; }
                else if (ph == 3) { st = 2 * i + 2; smat = 1; shalf = 1; }
                else if (ph == 4) { st = 2 * i + 2; smat = 0; shalf = 0; }
                else if (ph == 5) { st = 2 * i + 2; smat = 0; shalf = 1; }
                else if (ph == 6) { st = 2 * i + 3; smat = 1; shalf = 0; }
                else              { st = 2 * i + 3; smat = 1; shalf = 1; }
                if (st < 16) {
                    short* dst = sm + (st & 1) * 32768 + smat * 16384 + shalf * 8192;
                    const short* g = smat ? Bb : A;
                    int grow0 = (smat ? j0 : i0) + shalf * 128;
                    stage2(g, grow0, st * 64, dst, tid);
                }
            }
            __builtin_amdgcn_s_barrier();
            __builtin_amdgcn_s_setprio(1);
#pragma unroll
            for (int m2 = 0; m2 < 2; m2++)
#pragma unroll
                for (int nj = 0; nj < 4; nj++) {
                    acc[2 * q + m2][nj] = __builtin_amdgcn_mfma_f32_16x16x32_bf16(
                        av[m2 * 2 + 0], bv[nj * 2 + 0], acc[2 * q + m2][nj], 0, 0, 0);
                    acc[2 * q + m2][nj] = __builtin_amdgcn_mfma_f32_16x16x32_bf16(
                        av[m2 * 2 + 1], bv[nj * 2 + 1], acc[2 * q + m2][nj], 0, 0, 0);
                }
            __builtin_amdgcn_s_setprio(0);
            if (ph == 3 || ph == 7) {
                if (i < 7) asm volatile("s_waitcnt vmcnt(4)" ::: "memory");
                else       asm volatile("s_waitcnt vmcnt(0)" ::: "memory");
            }
            __builtin_amdgcn_s_barrier();
        }
    }
    float* Cb = C + (size_t)bz * NN * NN;
#pragma unroll
    for (int nj = 0; nj < 4; nj++) {
        int col = j0 + wn + nj * 16 + fr;
        float cs = 0.f;
#pragma unroll
        for (int m = 0; m < 8; m++) {
            int row = i0 + wm + m * 16 + fk * 4;
#pragma unroll
            for (int r = 0; r < 4; r++) {
                float e = expf(acc[m][nj][r]);
                Cb[(size_t)(row + r) * NN + col] = e;
                cs += e;
            }
        }
        cs += __shfl_xor(cs, 16);
        cs += __shfl_xor(cs, 32);
        if (ln < 16) atomicAdd(&colsum[(size_t)bz * NN + col], cs);
    }
}

// ---------------- MFMA bf16 NT GEMM (MODE 3: split-K fp32 atomicAdd) ----------------
template<int MODE>
__global__ __launch_bounds__(256) void mgemm(const short* __restrict__ A,
                                             const short* __restrict__ B,
                                             void* __restrict__ Cv,
                                             int Kd, int kchunk,
                                             int ldA, int ldB, int ldC,
                                             long sA, long sB, long sC,
                                             float* __restrict__ colsum)
{
    int bz = blockIdx.z;
    const short* Ab = A + (size_t)bz * sA;
    const short* Bb = B + (size_t)bz * sB;
    int i0 = blockIdx.y * 128, j0 = blockIdx.x * 128;
    __shared__ short sm[16384];
    int tid = threadIdx.x;
    int ln = tid & 63, wv = tid >> 6;
    int wm = (wv >> 1) * 64, wn = (wv & 1) * 64;
    int fr = ln & 15, fk = ln >> 4;
    f32x4 acc[4][4];
#pragma unroll
    for (int a = 0; a < 4; a++)
#pragma unroll
        for (int b2 = 0; b2 < 4; b2++) acc[a][b2] = (f32x4)(0.f);

    int k_lo = 0, k_hi = Kd;
    if constexpr (MODE == 3) { k_lo = bz * kchunk; k_hi = k_lo + kchunk; }

    for (int k0 = k_lo; k0 < k_hi; k0 += 64) {
#pragma unroll
        for (int q = 0; q < 4; q++) {
            int e = q * 2048 + tid * 8;
            const short* src = Ab + (size_t)(i0 + (e >> 6)) * ldA + k0 + (e & 63);
            gll16(src, sm + e);
        }
#pragma unroll
        for (int q = 0; q < 4; q++) {
            int e = q * 2048 + tid * 8;
            const short* src = Bb + (size_t)(j0 + (e >> 6)) * ldB + k0 + (e & 63);
            gll16(src, sm + 8192 + e);
        }
        __syncthreads();
#pragma unroll
        for (int ks = 0; ks < 2; ks++) {
            bf16x8 av[4], bv[4];
#pragma unroll
            for (int mi = 0; mi < 4; mi++)
                av[mi] = *(const bf16x8*)(sm + (wm + mi * 16 + fr) * 64 + ks * 32 + fk * 8);
#pragma unroll
            for (int nj = 0; nj < 4; nj++)
                bv[nj] = *(const bf16x8*)(sm + 8192 + (wn + nj * 16 + fr) * 64 + ks * 32 + fk * 8);
#pragma unroll
            for (int mi = 0; mi < 4; mi++)
#pragma unroll
                for (int nj = 0; nj < 4; nj++)
                    acc[mi][nj] = __builtin_amdgcn_mfma_f32_16x16x32_bf16(av[mi], bv[nj], acc[mi][nj], 0, 0, 0);
        }
        __syncthreads();
    }
    if constexpr (MODE == 3) {
        float* Cb = (float*)Cv;
#pragma unroll
        for (int mi = 0; mi < 4; mi++)
#pragma unroll
            for (int nj = 0; nj < 4; nj++) {
                int row = i0 + wm + mi * 16 + fk * 4;
                int col = j0 + wn + nj * 16 + fr;
#pragma unroll
                for (int r = 0; r < 4; r++)
                    atomicAdd(&Cb[(size_t)(row + r) * ldC + col], acc[mi][nj][r]);
            }
    }
}

// ---------------- merged h-GEMMs: 768 blocks, first 384 At1->h1, next 384 At2->h2 ----------------
__global__ __launch_bounds__(256) void mgemm_hh(const short* __restrict__ A1,
                                                const short* __restrict__ A2,
                                                const short* __restrict__ B,
                                                unsigned short* __restrict__ C1,
                                                unsigned short* __restrict__ C2)
{
    int id = blockIdx.x;
    int half = id / 384;
    int sid = id - half * 384;
    int xcd = sid & 7, jj = sid >> 3;
    int b = (xcd << 1) | (jj / 24);
    int r = jj % 24;
    int i0 = (r / 3) * 128, j0 = (r % 3) * 128;
    const short* Ab = (half ? A2 : A1) + (size_t)b * NN * NN;
    const short* Bb = B + (size_t)b * 384 * NN;
    unsigned short* C = half ? C2 : C1;
    __shared__ short sm[16384];
    int tid = threadIdx.x;
    int ln = tid & 63, wv = tid >> 6;
    int wm = (wv >> 1) * 64, wn = (wv & 1) * 64;
    int fr = ln & 15, fk = ln >> 4;
    f32x4 acc[4][4];
#pragma unroll
    for (int a = 0; a < 4; a++)
#pragma unroll
        for (int b2 = 0; b2 < 4; b2++) acc[a][b2] = (f32x4)(0.f);

    for (int k0 = 0; k0 < NN; k0 += 64) {
#pragma unroll
        for (int q = 0; q < 4; q++) {
            int e = q * 2048 + tid * 8;
            gll16(Ab + (size_t)(i0 + (e >> 6)) * NN + k0 + (e & 63), sm + e);
        }
#pragma unroll
        for (int q = 0; q < 4; q++) {
            int e = q * 2048 + tid * 8;
            gll16(Bb + (size_t)(j0 + (e >> 6)) * NN + k0 + (e & 63), sm + 8192 + e);
        }
        __syncthreads();
#pragma unroll
        for (int ks = 0; ks < 2; ks++) {
            bf16x8 av[4], bv[4];
#pragma unroll
            for (int mi = 0; mi < 4; mi++)
                av[mi] = *(const bf16x8*)(sm + (wm + mi * 16 + fr) * 64 + ks * 32 + fk * 8);
#pragma unroll
            for (int nj = 0; nj < 4; nj++)
                bv[nj] = *(const bf16x8*)(sm + 8192 + (wn + nj * 16 + fr) * 64 + ks * 32 + fk * 8);
#pragma unroll
            for (int mi = 0; mi < 4; mi++)
#pragma unroll
                for (int nj = 0; nj < 4; nj++)
                    acc[mi][nj] = __builtin_amdgcn_mfma_f32_16x16x32_bf16(av[mi], bv[nj], acc[mi][nj], 0, 0, 0);
        }
        __syncthreads();
    }
#pragma unroll
    for (int mi = 0; mi < 4; mi++)
#pragma unroll
        for (int nj = 0; nj < 4; nj++) {
            int row = i0 + wm + mi * 16 + fk * 4;
            int col = j0 + wn + nj * 16 + fr;
#pragma unroll
            for (int r2 = 0; r2 < 4; r2++)
                C[((size_t)b * NN + row + r2) * 384 + col] = cvt_bf(acc[mi][nj][r2]);
        }
}

// ---------------- normalize + threshold + At1 + At2 + sdiag (in-place fp32 spat) ----------------
__global__ __launch_bounds__(256) void k_normprep2(float* __restrict__ spat,
                                                   const float* __restrict__ colsum,
                                                   const float* __restrict__ sup,
                                                   const float* __restrict__ supsq,
                                                   unsigned short* __restrict__ At1,
                                                   unsigned short* __restrict__ At2,
                                                   float* __restrict__ sdiag)
{
    __shared__ unsigned short t1[64][66];
    __shared__ unsigned short t2[64][66];
    int b = blockIdx.z;
    int n0 = blockIdx.y * 64, m0 = blockIdx.x * 64;
    int tid = threadIdx.x;
    int c = tid & 63, r0 = tid >> 6;
    const float thr = (1.0f / 1024.0f) / 0.6f;
    float inv = 1.f / colsum[(size_t)b * NN + m0 + c];
    float* sp = spat + (size_t)b * NN * NN;
    for (int i = 0; i < 16; i++) {
        int r = r0 + i * 4;
        size_t idx = (size_t)(n0 + r) * NN + m0 + c;
        float v = sp[idx] * inv;
        v = (v < thr) ? 0.f : v;
        sp[idx] = v;
        if (n0 + r == m0 + c) sdiag[(size_t)b * NN + n0 + r] = v;
        t1[r][c] = cvt_bf(sup[(size_t)(n0 + r) * NN + m0 + c] * v);
        float p2 = 2.f * supsq[(size_t)(n0 + r) * NN + m0 + c]
                 - (((n0 + r) == (m0 + c)) ? 1.f : 0.f);
        t2[r][c] = cvt_bf(p2 * v);
    }
    __syncthreads();
    int c2 = tid & 31, r4 = tid >> 5;
    size_t ob = ((size_t)b * NN + m0) * NN + n0;
    for (int i = 0; i < 8; i++) {
        int rr = r4 + i * 8;
        unsigned int v1 = (unsigned int)t1[2 * c2][rr] | ((unsigned int)t1[2 * c2 + 1][rr] << 16);
        unsigned int v2 = (unsigned int)t2[2 * c2][rr] | ((unsigned int)t2[2 * c2 + 1][rr] << 16);
        *(unsigned int*)(At1 + ob + (size_t)rr * NN + 2 * c2) = v1;
        *(unsigned int*)(At2 + ob + (size_t)rr * NN + 2 * c2) = v2;
    }
}

// ---------------- support graph (also zeroes its supsq row) ----------------
__global__ __launch_bounds__(256) void k_sup(const float* __restrict__ emb,
                                             float* __restrict__ sup,
                                             unsigned short* __restrict__ supB,
                                             float* __restrict__ supsq)
{
    int n = blockIdx.x, tid = threadIdx.x;
    {
        float4 z; z.x = 0.f; z.y = 0.f; z.z = 0.f; z.w = 0.f;
        *(float4*)(supsq + (size_t)n * NN + tid * 4) = z;
    }
    __shared__ float en[16];
    if (tid < 16) en[tid] = emb[n * 16 + tid];
    __syncthreads();
    float v[4];
#pragma unroll
    for (int q = 0; q < 4; q++) {
        int m = q * 256 + tid;
        float d = 0.f;
#pragma unroll
        for (int dd = 0; dd < 16; dd++) d += en[dd] * emb[m * 16 + dd];
        v[q] = fmaxf(d, 0.f);
    }
    float mx = fmaxf(fmaxf(v[0], v[1]), fmaxf(v[2], v[3]));
    for (int o = 32; o > 0; o >>= 1) mx = fmaxf(mx, __shfl_xor(mx, o));
    __shared__ float red[4];
    if ((tid & 63) == 0) red[tid >> 6] = mx;
    __syncthreads();
    mx = fmaxf(fmaxf(red[0], red[1]), fmaxf(red[2], red[3]));
    float e[4];
    float s = 0.f;
#pragma unroll
    for (int q = 0; q < 4; q++) { e[q] = expf(v[q] - mx); s += e[q]; }
    for (int o = 32; o > 0; o >>= 1) s += __shfl_xor(s, o);
    __shared__ float red2[4];
    if ((tid & 63) == 0) red2[tid >> 6] = s;
    __syncthreads();
    s = red2[0] + red2[1] + red2[2] + red2[3];
    float inv = 1.f / s;
#pragma unroll
    for (int q = 0; q < 4; q++) {
        float val = e[q] * inv;
        sup[(size_t)n * NN + q * 256 + tid] = val;
        supB[(size_t)n * NN + q * 256 + tid] = cvt_bf(val);
    }
}

// ---------------- merged weight prep ----------------
__global__ __launch_bounds__(256) void k_wprep(const float* __restrict__ tcv,
                                               const float* __restrict__ tcg,
                                               const float* __restrict__ Theta,
                                               const float* __restrict__ rcw,
                                               unsigned short* __restrict__ Wr,
                                               unsigned short* __restrict__ Th,
                                               unsigned short* __restrict__ Rc)
{
    int tid = threadIdx.x;
    if (blockIdx.x < 64) {
        int o = blockIdx.x;
        float t = 0.f, p = 0.f;
        if (tid < 192) { t = tcv[o * 192 + tid]; p = t * t; }
        for (int off = 32; off > 0; off >>= 1) p += __shfl_xor(p, off);
        __shared__ float wsr[3];
        if (tid < 192 && (tid & 63) == 0) wsr[tid >> 6] = p;
        __syncthreads();
        if (tid < 192) {
            float sum = wsr[0] + wsr[1] + wsr[2];
            int c = tid / 3, dt = tid - c * 3;
            Wr[o * 192 + dt * 64 + c] = cvt_bf(t * (tcg[o] / sqrtf(sum)));
        }
    } else {
        for (int i = tid; i < 6144; i += 256) {
            int o = i / 96, rem = i - o * 96;
            int kind = rem >> 5, f = rem & 31;
            Th[i] = cvt_bf(Theta[kind * 2048 + f * 64 + o]);
        }
        for (int i = tid; i < 2048; i += 256) Rc[i] = cvt_bf(rcw[i]);
    }
}

// ---------------- MFMA fused tail (reads x fp32) ----------------
__global__ __launch_bounds__(256) void k_tail(const float* __restrict__ x,
                                              const unsigned short* __restrict__ h1,
                                              const unsigned short* __restrict__ h2,
                                              const float* __restrict__ sdiag,
                                              const unsigned short* __restrict__ Th,
                                              const unsigned short* __restrict__ Wr,
                                              const unsigned short* __restrict__ Rc,
                                              const float* __restrict__ tcb,
                                              const float* __restrict__ rcb,
                                              const float* __restrict__ lnw,
                                              const float* __restrict__ lnb,
                                              float* __restrict__ out)
{
    int b = blockIdx.y;
    int node0 = blockIdx.x * 4;
    int tid = threadIdx.x;
    int ln = tid & 63, wv = tid >> 6;
    int fr = ln & 15, fk = ln >> 4;

    __shared__ union {
        struct { unsigned short xt[1920], h1t[1920], h2t[1920], gcn[4032]; } a;
        float Y[48 * 65];
    } u;
    __shared__ float sdp[48];
    __shared__ float lnwS[64], lnbS[64], tbS[64];
    __shared__ float muS[48], rsS[48];

    size_t rowb = ((size_t)b * NN + node0) * 384;
    {
        const float2* xp = (const float2*)(x + rowb);
        const unsigned int* h1p = (const unsigned int*)(h1 + rowb);
        const unsigned int* h2p = (const unsigned int*)(h2 + rowb);
        for (int q = tid; q < 768; q += 256) {
            int j0 = q * 2;
            int node = j0 / 384, j = j0 - node * 384;
            int f = j / 12, t = j - f * 12;
            int t2 = t + 1, f2 = f;
            if (t2 == 12) { t2 = 0; f2 = f + 1; }
            int la0 = node * 480 + t * 40 + f;
            int la1 = node * 480 + t2 * 40 + f2;
            float2 xv = xp[q];
            unsigned int w1 = h1p[q], w2 = h2p[q];
            u.a.xt[la0] = cvt_bf(xv.x);  u.a.xt[la1] = cvt_bf(xv.y);
            u.a.h1t[la0] = (unsigned short)(w1 & 0xffff); u.a.h1t[la1] = (unsigned short)(w1 >> 16);
            u.a.h2t[la0] = (unsigned short)(w2 & 0xffff); u.a.h2t[la1] = (unsigned short)(w2 >> 16);
        }
    }
    for (int i = tid; i < 576; i += 256) {
        int node = i / 144, r = i - node * 144;
        int rr = (r < 72) ? 0 : 13;
        u.a.gcn[node * 1008 + rr * 72 + (r % 72)] = 0;
    }
    if (tid < 48) sdp[tid] = sdiag[(size_t)b * NN + node0 + tid / 12];
    if (tid < 64) { lnwS[tid] = lnw[tid]; lnbS[tid] = lnb[tid]; tbS[tid] = tcb[tid] + rcb[tid]; }

    int ocol = wv * 16 + fr;
    bf16x8 bTh[3], bWr[6], bRc;
#pragma unroll
    for (int kb = 0; kb < 3; kb++)
        bTh[kb] = *(const bf16x8*)((const short*)Th + (size_t)ocol * 96 + kb * 32 + fk * 8);
#pragma unroll
    for (int kb = 0; kb < 6; kb++)
        bWr[kb] = *(const bf16x8*)((const short*)Wr + (size_t)ocol * 192 + kb * 32 + fk * 8);
    bRc = *(const bf16x8*)((const short*)Rc + (size_t)ocol * 32 + fk * 8);

    int na[3], ta[3];
#pragma unroll
    for (int rb = 0; rb < 3; rb++) {
        int p = rb * 16 + fr;
        na[rb] = p / 12; ta[rb] = p - na[rb] * 12;
    }
    __syncthreads();

    f32x4 acc[3];
#pragma unroll
    for (int rb = 0; rb < 3; rb++) {
        int ax = na[rb] * 480 + ta[rb] * 40 + fk * 8;
        bf16x8 avx = *(const bf16x8*)(u.a.xt + ax);
        f32x4 z = (f32x4)(0.f);
        acc[rb] = __builtin_amdgcn_mfma_f32_16x16x32_bf16(avx, bTh[0], z, 0, 0, 0);
#pragma unroll
        for (int r = 0; r < 4; r++) acc[rb][r] *= sdp[rb * 16 + fk * 4 + r];
        bf16x8 av1 = *(const bf16x8*)(u.a.h1t + ax);
        acc[rb] = __builtin_amdgcn_mfma_f32_16x16x32_bf16(av1, bTh[1], acc[rb], 0, 0, 0);
        bf16x8 av2 = *(const bf16x8*)(u.a.h2t + ax);
        acc[rb] = __builtin_amdgcn_mfma_f32_16x16x32_bf16(av2, bTh[2], acc[rb], 0, 0, 0);
    }
#pragma unroll
    for (int rb = 0; rb < 3; rb++) {
#pragma unroll
        for (int r = 0; r < 4; r++) {
            int pc = rb * 16 + fk * 4 + r;
            int nc = pc / 12, tc2 = pc - nc * 12;
            u.a.gcn[nc * 1008 + (tc2 + 1) * 72 + wv * 16 + fr] = cvt_bf(fmaxf(acc[rb][r], 0.f));
        }
    }
    __syncthreads();
#pragma unroll
    for (int rb = 0; rb < 3; rb++) {
        f32x4 a2 = (f32x4)(0.f);
#pragma unroll
        for (int kb = 0; kb < 6; kb++) {
            int dt = kb >> 1, c0 = (kb & 1) * 32;
            bf16x8 ag = *(const bf16x8*)(u.a.gcn + na[rb] * 1008 + (ta[rb] + dt) * 72 + c0 + fk * 8);
            a2 = __builtin_amdgcn_mfma_f32_16x16x32_bf16(ag, bWr[kb], a2, 0, 0, 0);
        }
        int ax = na[rb] * 480 + ta[rb] * 40 + fk * 8;
        bf16x8 avx = *(const bf16x8*)(u.a.xt + ax);
        acc[rb] = __builtin_amdgcn_mfma_f32_16x16x32_bf16(avx, bRc, a2, 0, 0, 0);
    }
    __syncthreads();
    float tb = tbS[ocol];
#pragma unroll
    for (int rb = 0; rb < 3; rb++)
#pragma unroll
        for (int r = 0; r < 4; r++)
            u.Y[(rb * 16 + fk * 4 + r) * 65 + ocol] = acc[rb][r] + tb;
    __syncthreads();
    if (tid < 48) {
        float s = 0.f, s2 = 0.f;
        for (int o = 0; o < 64; o++) {
            float v = u.Y[tid * 65 + o];
            s += v; s2 += v * v;
        }
        float mm = s * (1.f / 64.f);
        float var = s2 * (1.f / 64.f) - mm * mm;
        muS[tid] = mm; rsS[tid] = rsqrtf(var + 1e-5f);
    }
    __syncthreads();
    float2* obv = (float2*)(out + rowb * 2);
    for (int q = tid; q < 1536; q += 256) {
        int i = q * 2;
        int node = i / 768, rr = i - node * 768;
        int o = rr / 12, t = rr - o * 12;
        int p0 = node * 12 + t;
        float v0 = (u.Y[p0 * 65 + o] - muS[p0]) * rsS[p0] * lnwS[o] + lnbS[o];
        int t1 = t + 1, o1 = o;
        if (t1 == 12) { t1 = 0; o1 = o + 1; }
        int p1 = node * 12 + t1;
        float v1 = (u.Y[p1 * 65 + o1] - muS[p1]) * rsS[p1] * lnwS[o1] + lnbS[o1];
        float2 pk; pk.x = v0; pk.y = v1;
        obv[q] = pk;
    }
}

extern "C" void kernel_launch(void* const* d_in, const int* in_sizes, int n_in,
                              void* d_out, int out_size, void* d_ws, size_t ws_size,
                              hipStream_t stream)
{
    const float* x    = (const float*)d_in[0];
    const float* emb  = (const float*)d_in[1];
    const float* W1   = (const float*)d_in[2];
    const float* W2   = (const float*)d_in[3];
    const float* W3   = (const float*)d_in[4];
    const float* bs   = (const float*)d_in[5];
    const float* Vs   = (const float*)d_in[6];
    const float* U1   = (const float*)d_in[7];
    const float* U2   = (const float*)d_in[8];
    const float* U3   = (const float*)d_in[9];
    const float* be   = (const float*)d_in[10];
    const float* Ve   = (const float*)d_in[11];
    const float* Theta= (const float*)d_in[12];
    const float* tcv  = (const float*)d_in[13];
    const float* tcg  = (const float*)d_in[14];
    const float* tcb  = (const float*)d_in[15];
    const float* rcw  = (const float*)d_in[16];
    const float* rcb  = (const float*)d_in[17];
    const float* lnw  = (const float*)d_in[18];
    const float* lnb  = (const float*)d_in[19];

    float* xres = (float*)d_out;                       // B*N*FT*T fp32 (scratch for At2 until k_tail)
    float* spat = xres + (size_t)NB * NN * NFT * NT;   // B*N*N fp32

    char* base = (char*)d_ws;                          // round-11 compact aliased layout (~90 MB)
    unsigned short* Xrow = (unsigned short*)(base + 0);
    unsigned short* Pt   = (unsigned short*)(base + 0);
    unsigned short* supB = (unsigned short*)(base + 0);
    unsigned short* supT = (unsigned short*)(base + 2097152);
    unsigned short* At1  = (unsigned short*)(base + 0);
    unsigned short* At2  = (unsigned short*)xres;          // d_out scratch
    unsigned short* Xt  = (unsigned short*)(base + 33554432);
    unsigned short* h1  = (unsigned short*)(base + 46137344);
    unsigned short* h2  = (unsigned short*)(base + 58720256);
    unsigned short* Vsb = (unsigned short*)(base + 71303168);
    float* colsum  = (float*)(base + 73400320);
    float* sdiag   = (float*)(base + 73465856);
    float* sup     = (float*)(base + 77594624);
    float* supsq   = (float*)(base + 81788928);
    float* lhs_pre = (float*)(base + 85983232);
    float* M2      = (float*)(base + 86007808);
    float* rhs     = (float*)(base + 86794240);
    float* rr3     = (float*)(base + 87580672);
    float* E       = (float*)(base + 88376320);
    float* EW1     = (float*)(base + 88385536);
    float* l2      = (float*)(base + 88386560);
    float* r2      = (float*)(base + 89172992);
    unsigned short* Wr = (unsigned short*)(base + 89959424);
    unsigned short* Th = (unsigned short*)(base + 89984000);
    unsigned short* Rc = (unsigned short*)(base + 89996288);

    hipMemsetAsync(lhs_pre, 0, 49152, stream);             // lhs_pre + M2 (contiguous)

    // pre-pass: x fp32 -> lhs_pre, rhs, rr3, Xrow(bf16)
    k_pre<<<dim3(16, 16), 384, 0, stream>>>(x, U1, U3, W3, lhs_pre, rhs, rr3, Xrow);
    k_M2<<<dim3(16, 32), 384, 0, stream>>>(U2, rhs, M2);
    k_E<<<16, 192, 0, stream>>>(lhs_pre, M2, be, Ve, W1, E, EW1);
    // spatial attention
    k_l2r2x<<<dim3(128, 16), 384, 0, stream>>>(Xrow, rr3, E, EW1, W2, l2, r2);
    k_xt<<<dim3(6, 16, 16), 256, 0, stream>>>(Xrow, Xt, Vs, Vsb);  // before Pt overwrites Xrow
    k_Ptile<<<dim3(16, 16, 16), 256, 0, stream>>>(l2, r2, bs, Pt, colsum);  // also zeroes colsum
    // 8-phase 256^2 S-GEMM with exp+colsum epilogue (fp32 spat direct)
    sgemm8<<<dim3(4, 4, 16), 512, 0, stream>>>((const short*)Vsb, (const short*)Pt,
                                               spat, colsum);
    // graph supports (k_sup zeroes supsq rows)
    k_sup<<<1024, 256, 0, stream>>>(emb, sup, supB, supsq);
    k_tb16<<<dim3(16, 16), 256, 0, stream>>>(supB, supT);
    mgemm<3><<<dim3(8, 8, 4), 256, 0, stream>>>((const short*)supB, (const short*)supT,
        (void*)supsq, NN, 256, NN, NN, NN, 0L, 0L, 0L, nullptr);
    // normalize + threshold + masked adjacencies + diagonal
    k_normprep2<<<dim3(16, 16, 16), 256, 0, stream>>>(spat, colsum, sup, supsq, At1, At2, sdiag);
    // merged h-GEMMs (768 blocks, XCD swizzle per half)
    mgemm_hh<<<768, 256, 0, stream>>>((const short*)At1, (const short*)At2,
                                      (const short*)Xt, h1, h2);
    // tail
    k_wprep<<<65, 256, 0, stream>>>(tcv, tcg, Theta, rcw, Wr, Th, Rc);
    k_tail<<<dim3(256, 16), 256, 0, stream>>>(x, h1, h2, sdiag, Th, Wr, Rc,
                                              tcb, rcb, lnw, lnb, xres);
}